// Round 1
// baseline (887.897 us; speedup 1.0000x reference)
//
#include <hip/hip_runtime.h>
#include <hip/hip_bf16.h>
#include <stdint.h>
#include <type_traits>

#define DEVINL __device__ __forceinline__

typedef unsigned short u16;
typedef unsigned int   u32;
typedef short bf16x8 __attribute__((ext_vector_type(8)));
typedef float f32x4  __attribute__((ext_vector_type(4)));

// ---- problem constants ----
constexpr int BB   = 2,  SS  = 2048, HID = 2048, NH = 16;
constexpr int NOPE = 128, VD = 128, QHD = 192;
constexpr int QL   = 1536, KVL = 512;
constexpr int TOK  = BB * SS;            // 4096 tokens
constexpr int KVPAD = 640;               // kv_a rows 576 padded to 640
constexpr int NCOMB = QL + KVPAD;        // 2176 combined q_a+kv_a output dim
constexpr float SCALE     = 0.07216878364870322f;   // 192^-0.5
constexpr float LN1E4_32  = 0.28782313662425575f;   // ln(10000)/32

DEVINL float bf2f(u16 u) { union { u32 u; float f; } v; v.u = (u32)u << 16; return v.f; }
DEVINL u16 f2bf(float f) {
  union { float f; u32 u; } v; v.f = f;
  u32 r = v.u + 0x7fffu + ((v.u >> 16) & 1u);
  return (u16)(r >> 16);
}
DEVINL u32 pack2(float a, float b) { return (u32)f2bf(a) | ((u32)f2bf(b) << 16); }

DEVINL void gload_lds16(const u16* g, u16* l) {
  __builtin_amdgcn_global_load_lds(
      (const __attribute__((address_space(1))) void*)g,
      (__attribute__((address_space(3))) void*)l, 16, 0, 0);
}

// ---------------- fp32 -> bf16 conversion ----------------
__global__ void k_f2bf(const float* __restrict__ s, u16* __restrict__ d, int n) {
  int i = (blockIdx.x * 256 + threadIdx.x) * 4;
  if (i + 4 <= n) {
    float4 v = *(const float4*)(s + i);
    uint2 o; o.x = pack2(v.x, v.y); o.y = pack2(v.z, v.w);
    *(uint2*)(d + i) = o;
  } else {
    for (; i < n; ++i) d[i] = f2bf(s[i]);
  }
}

// convert with zero row padding (src: srows x cols, dst: drows x cols)
__global__ void k_f2bf_pad(const float* __restrict__ s, u16* __restrict__ d,
                           int srows, int cols, int drows) {
  int i = (blockIdx.x * 256 + threadIdx.x) * 4;
  int n = drows * cols;
  if (i + 4 > n) return;
  int row = i / cols;
  uint2 o;
  if (row < srows) {
    float4 v = *(const float4*)(s + i);
    o.x = pack2(v.x, v.y); o.y = pack2(v.z, v.w);
  } else {
    o.x = 0u; o.y = 0u;
  }
  *(uint2*)(d + i) = o;
}

// ---------------- NT GEMM: C[M][N] = A[M][K] * Bw[N][K]^T (bf16 in, OutT out) ----------------
// 128x128 tile, 4 waves (2x2), 16x16x32 bf16 MFMA, global_load_lds staging,
// source-side XOR swizzle: slot ^= (row ^ row>>2) & 3 (LDS dest stays linear).
template <typename OutT>
__global__ __launch_bounds__(256)
void k_gemm_bt(const u16* __restrict__ A, const u16* __restrict__ Bw,
               OutT* __restrict__ C, int M, int N, int K) {
  __shared__ u16 As[128 * 32];
  __shared__ u16 Bs[128 * 32];
  const int t = threadIdx.x;
  const int lane = t & 63, wave = t >> 6;
  const int wr = wave >> 1, wc = wave & 1;
  const int lq = lane & 15, lg = lane >> 4;
  const int m0 = blockIdx.y * 128, n0 = blockIdx.x * 128;

  f32x4 acc[4][4] = {};

  for (int k0 = 0; k0 < K; k0 += 32) {
#pragma unroll
    for (int i = 0; i < 2; ++i) {
      const int ebase = i * 256 + wave * 64;     // wave-uniform LDS base (16B units)
      const int e = ebase + lane;
      const int row = e >> 2, sl = e & 3;
      const int sg = sl ^ ((row ^ (row >> 2)) & 3);
      gload_lds16(A  + (size_t)(m0 + row) * K + (k0 + sg * 8), As + ebase * 8);
      gload_lds16(Bw + (size_t)(n0 + row) * K + (k0 + sg * 8), Bs + ebase * 8);
    }
    __syncthreads();

    bf16x8 af[4], bfv[4];
#pragma unroll
    for (int x = 0; x < 4; ++x) {
      int ra = wr * 64 + x * 16 + lq;
      af[x]  = *(const bf16x8*)(As + ra * 32 + (lg ^ ((ra ^ (ra >> 2)) & 3)) * 8);
      int rb = wc * 64 + x * 16 + lq;
      bfv[x] = *(const bf16x8*)(Bs + rb * 32 + (lg ^ ((rb ^ (rb >> 2)) & 3)) * 8);
    }
#pragma unroll
    for (int mi = 0; mi < 4; ++mi)
#pragma unroll
      for (int ni = 0; ni < 4; ++ni)
        acc[mi][ni] = __builtin_amdgcn_mfma_f32_16x16x32_bf16(af[mi], bfv[ni], acc[mi][ni], 0, 0, 0);
    __syncthreads();
  }

#pragma unroll
  for (int mi = 0; mi < 4; ++mi)
#pragma unroll
    for (int ni = 0; ni < 4; ++ni)
#pragma unroll
      for (int r = 0; r < 4; ++r) {
        int row = m0 + wr * 64 + mi * 16 + lg * 4 + r;
        int col = n0 + wc * 64 + ni * 16 + lq;
        float v = acc[mi][ni][r];
        if constexpr (std::is_same<OutT, float>::value)
          C[(size_t)row * N + col] = v;
        else
          C[(size_t)row * N + col] = f2bf(v);
      }
}

// ---------------- RMSNorm (row-wise, fp32 math, bf16 in/out) ----------------
__global__ __launch_bounds__(256)
void k_rmsnorm(const u16* __restrict__ x, const float* __restrict__ w,
               u16* __restrict__ y, int D, int xstride) {
  const int row = blockIdx.x;
  const u16* xr = x + (size_t)row * xstride;
  float ss = 0.f;
  for (int i = threadIdx.x; i < D; i += 256) { float v = bf2f(xr[i]); ss += v * v; }
#pragma unroll
  for (int o = 1; o < 64; o <<= 1) ss += __shfl_xor(ss, o);
  __shared__ float red[4];
  if ((threadIdx.x & 63) == 0) red[threadIdx.x >> 6] = ss;
  __syncthreads();
  float rs = rsqrtf((red[0] + red[1] + red[2] + red[3]) / (float)D + 1e-6f);
  u16* yr = y + (size_t)row * D;
  for (int i = threadIdx.x; i < D; i += 256) yr[i] = f2bf(bf2f(xr[i]) * rs * w[i]);
}

// ---------------- pack Q: (tok, H*192) -> (B,H,S,192) with RoPE on d in [128,192) ----------------
// interleaved rope: out[j] = x[2j]c - x[2j+1]s ; out[j+32] = x[2j+1]c + x[2j]s
__global__ void k_pack_q(const u16* __restrict__ qf, const int* __restrict__ pos,
                         u16* __restrict__ Qp) {
  int idx = blockIdx.x * 256 + threadIdx.x;
  int d = idx % QHD;
  int r0 = idx / QHD;
  int s = r0 % SS;
  int bh = r0 / SS;
  int b = bh >> 4, h = bh & 15;
  int token = b * SS + s;
  const u16* src = qf + (size_t)token * (NH * QHD) + h * QHD;
  u16 outv;
  if (d < NOPE) {
    outv = src[d];
  } else {
    int rr = d - NOPE;
    int j = rr & 31;
    float x0 = bf2f(src[NOPE + 2 * j]), x1 = bf2f(src[NOPE + 2 * j + 1]);
    float ang = (float)pos[b * SS + s] * __expf(-(float)j * LN1E4_32);
    float sn, c; sincosf(ang, &sn, &c);
    outv = f2bf(rr < 32 ? (x0 * c - x1 * sn) : (x1 * c + x0 * sn));
  }
  Qp[idx] = outv;
}

// ---------------- pack K: k_nope from kvfull, roped k_pe from combined q_a/kv_a output ----------------
__global__ void k_pack_k(const u16* __restrict__ kvf, const u16* __restrict__ ac,
                         const int* __restrict__ pos, u16* __restrict__ Kp) {
  int idx = blockIdx.x * 256 + threadIdx.x;
  int d = idx % QHD;
  int r0 = idx / QHD;
  int s = r0 % SS;
  int bh = r0 / SS;
  int b = bh >> 4, h = bh & 15;
  int token = b * SS + s;
  u16 outv;
  if (d < NOPE) {
    outv = kvf[(size_t)token * (NH * 256) + h * 256 + d];
  } else {
    const u16* pe = ac + (size_t)token * NCOMB + (QL + KVL);  // k_pe cols (64)
    int rr = d - NOPE;
    int j = rr & 31;
    float x0 = bf2f(pe[2 * j]), x1 = bf2f(pe[2 * j + 1]);
    float ang = (float)pos[b * SS + s] * __expf(-(float)j * LN1E4_32);
    float sn, c; sincosf(ang, &sn, &c);
    outv = f2bf(rr < 32 ? (x0 * c - x1 * sn) : (x1 * c + x0 * sn));
  }
  Kp[idx] = outv;
}

// ---------------- pack V^T: (B,H,VD,S) ----------------
__global__ void k_pack_v(const u16* __restrict__ kvf, u16* __restrict__ VT) {
  int idx = blockIdx.x * 256 + threadIdx.x;
  int s = idx & (SS - 1);
  int r0 = idx >> 11;
  int v = r0 & 127;
  int bh = r0 >> 7;
  int b = bh >> 4, h = bh & 15;
  VT[idx] = kvf[(size_t)(b * SS + s) * (NH * 256) + h * 256 + NOPE + v];
}

// ---------------- causal flash attention ----------------
// grid (S/64, B*H), 4 waves/block; wave w owns q rows q0 = blk*64 + w*16.
// Swapped QK^T: S^T = mfma(K_frag, Q_frag); softmax over keys (4 regs + shfl 16/32);
// P transposed via 1KB swizzled per-wave LDS to feed PV B-operand; PV A = V^T rows.
__global__ __launch_bounds__(256)
void k_attn(const u16* __restrict__ Qp, const u16* __restrict__ Kp,
            const u16* __restrict__ VT, u16* __restrict__ Oa) {
  const int bh = blockIdx.y;
  const int t = threadIdx.x, lane = t & 63, wave = t >> 6;
  const int lq = lane & 15, lg = lane >> 4;
  const int q0 = blockIdx.x * 64 + wave * 16;
  const size_t qkb = (size_t)bh * SS * QHD;
  const size_t vb  = (size_t)bh * VD * SS;

  __shared__ u16 Pl[4][512];          // per-wave 16q x 32k bf16
  char* pl = (char*)&Pl[wave][0];
  const int swq = ((lq ^ (lq >> 2)) & 3) << 4;

  bf16x8 qf[6];
#pragma unroll
  for (int ch = 0; ch < 6; ++ch)
    qf[ch] = *(const bf16x8*)(Qp + qkb + (size_t)(q0 + lq) * QHD + ch * 32 + lg * 8);

  float m = -1e30f, lsum = 0.f;
  f32x4 o[8];
#pragma unroll
  for (int vc = 0; vc < 8; ++vc) o[vc] = (f32x4){0.f, 0.f, 0.f, 0.f};

  const int kend = q0 + 16;           // keys [0, kend)
  for (int kb = 0; kb < kend; kb += 32) {
    const bool hasHi = (kb + 16) < kend;
    f32x4 slo = (f32x4){0.f, 0.f, 0.f, 0.f};
    f32x4 shi = (f32x4){0.f, 0.f, 0.f, 0.f};
#pragma unroll
    for (int ch = 0; ch < 6; ++ch) {
      bf16x8 kf = *(const bf16x8*)(Kp + qkb + (size_t)(kb + lq) * QHD + ch * 32 + lg * 8);
      slo = __builtin_amdgcn_mfma_f32_16x16x32_bf16(kf, qf[ch], slo, 0, 0, 0);
    }
    if (hasHi) {
#pragma unroll
      for (int ch = 0; ch < 6; ++ch) {
        bf16x8 kf = *(const bf16x8*)(Kp + qkb + (size_t)(kb + 16 + lq) * QHD + ch * 32 + lg * 8);
        shi = __builtin_amdgcn_mfma_f32_16x16x32_bf16(kf, qf[ch], shi, 0, 0, 0);
      }
    }
    const int qrow = q0 + lq;
    float mx = -1e30f;
#pragma unroll
    for (int r = 0; r < 4; ++r) {
      int klo = kb + lg * 4 + r;
      float v0 = (klo <= qrow) ? slo[r] * SCALE : -1e30f;
      float v1 = (hasHi && (klo + 16) <= qrow) ? shi[r] * SCALE : -1e30f;
      slo[r] = v0; shi[r] = v1;
      mx = fmaxf(mx, fmaxf(v0, v1));
    }
    mx = fmaxf(mx, __shfl_xor(mx, 16));
    mx = fmaxf(mx, __shfl_xor(mx, 32));
    float mnew = fmaxf(m, mx);
    float fac = __expf(m - mnew);
    float p0 = __expf(slo[0] - mnew), p1 = __expf(slo[1] - mnew);
    float p2 = __expf(slo[2] - mnew), p3 = __expf(slo[3] - mnew);
    float p4 = __expf(shi[0] - mnew), p5 = __expf(shi[1] - mnew);
    float p6 = __expf(shi[2] - mnew), p7 = __expf(shi[3] - mnew);
    float ps = ((p0 + p1) + (p2 + p3)) + ((p4 + p5) + (p6 + p7));
    ps += __shfl_xor(ps, 16);
    ps += __shfl_xor(ps, 32);
    lsum = lsum * fac + ps;
    m = mnew;
#pragma unroll
    for (int vc = 0; vc < 8; ++vc) {
      o[vc][0] *= fac; o[vc][1] *= fac; o[vc][2] *= fac; o[vc][3] *= fac;
    }
    // P^T -> LDS (row = q, logical byte = key*2, physical ^= swq on 16B slot bits)
    *(u32*)(pl + lq * 64 + ((8 * lg)          ^ swq)) = pack2(p0, p1);
    *(u32*)(pl + lq * 64 + ((8 * lg + 4)      ^ swq)) = pack2(p2, p3);
    *(u32*)(pl + lq * 64 + ((32 + 8 * lg)     ^ swq)) = pack2(p4, p5);
    *(u32*)(pl + lq * 64 + ((32 + 8 * lg + 4) ^ swq)) = pack2(p6, p7);
    bf16x8 pf = *(const bf16x8*)(pl + lq * 64 + ((16 * lg) ^ swq));
#pragma unroll
    for (int vc = 0; vc < 8; ++vc) {
      bf16x8 vf = *(const bf16x8*)(VT + vb + (size_t)(vc * 16 + lq) * SS + kb + lg * 8);
      o[vc] = __builtin_amdgcn_mfma_f32_16x16x32_bf16(vf, pf, o[vc], 0, 0, 0);
    }
  }

  const float inv = 1.0f / lsum;
  const int b = bh >> 4, h = bh & 15;
  u16* orow = Oa + (size_t)(b * SS + q0 + lq) * (NH * VD) + h * VD;
#pragma unroll
  for (int vc = 0; vc < 8; ++vc)
#pragma unroll
    for (int r = 0; r < 4; ++r)
      orow[vc * 16 + lg * 4 + r] = f2bf(o[vc][r] * inv);
}

// ---------------- host launch ----------------
extern "C" void kernel_launch(void* const* d_in, const int* in_sizes, int n_in,
                              void* d_out, int out_size, void* d_ws, size_t ws_size,
                              hipStream_t stream) {
  (void)in_sizes; (void)n_in; (void)out_size; (void)ws_size;
  const float* hidden  = (const float*)d_in[0];
  /* d_in[1] attention_mask: exactly triu(-1e9) causal -> applied analytically */
  const int*   pos     = (const int*)d_in[2];
  const float* q_a_w   = (const float*)d_in[3];
  const float* q_a_ln  = (const float*)d_in[4];
  const float* q_b_w   = (const float*)d_in[5];
  const float* kv_a_w  = (const float*)d_in[6];
  const float* kv_a_ln = (const float*)d_in[7];
  const float* kv_b_w  = (const float*)d_in[8];
  const float* o_w     = (const float*)d_in[9];

  char* ws = (char*)d_ws;
  // region map (bytes). reuse is ordered: ac/qa_n die before Qpk, qfull dies before attn_o.
  u16* hid_bf = (u16*)(ws + 0);          // 16,777,216   (later reused as VT)
  u16* VT     = (u16*)(ws + 0);
  u16* w_comb = (u16*)(ws + 16777216);   //  8,912,896  (q_a rows 0..1535, kv_a rows 1536..2175 padded)
  u16* w_qb   = (u16*)(ws + 25690112);   //  9,437,184
  u16* w_kvb  = (u16*)(ws + 35127296);   //  4,194,304
  u16* w_o    = (u16*)(ws + 39321600);   //  8,388,608
  u16* ac     = (u16*)(ws + 47710208);   // 17,825,792  (TOK x 2176)
  u16* qa_n   = (u16*)(ws + 65536000);   // 12,582,912
  u16* Qpk    = (u16*)(ws + 47710208);   // 25,165,824  (over ac+qa_n, after pack_k)
  u16* kv_n   = (u16*)(ws + 78118912);   //  4,194,304
  u16* qfull  = (u16*)(ws + 82313216);   // 25,165,824
  u16* attn_o = (u16*)(ws + 82313216);   // 16,777,216  (over qfull, after pack_q)
  u16* kvfull = (u16*)(ws + 107479040);  // 33,554,432
  u16* Kpk    = (u16*)(ws + 141033472);  // 25,165,824  -> total 166,199,296 B

  // fp32 -> bf16 conversions
  k_f2bf<<<(TOK * HID) / 1024, 256, 0, stream>>>(hidden, hid_bf, TOK * HID);
  k_f2bf<<<(QL * HID) / 1024, 256, 0, stream>>>(q_a_w, w_comb, QL * HID);
  k_f2bf_pad<<<(KVPAD * HID) / 1024, 256, 0, stream>>>(kv_a_w, w_comb + QL * HID, KVL + 64, HID, KVPAD);
  k_f2bf<<<(NH * QHD * QL) / 1024, 256, 0, stream>>>(q_b_w, w_qb, NH * QHD * QL);
  k_f2bf<<<(NH * 256 * KVL) / 1024, 256, 0, stream>>>(kv_b_w, w_kvb, NH * 256 * KVL);
  k_f2bf<<<(HID * NH * VD) / 1024, 256, 0, stream>>>(o_w, w_o, HID * NH * VD);

  // q_a + kv_a combined: (TOK,2048) @ (2176,2048)^T
  k_gemm_bt<u16><<<dim3(NCOMB / 128, TOK / 128), 256, 0, stream>>>(hid_bf, w_comb, ac, TOK, NCOMB, HID);
  // RMS norms
  k_rmsnorm<<<TOK, 256, 0, stream>>>(ac,      q_a_ln,  qa_n, QL,  NCOMB);
  k_rmsnorm<<<TOK, 256, 0, stream>>>(ac + QL, kv_a_ln, kv_n, KVL, NCOMB);
  // q_b: (TOK,1536)@(3072,1536)^T ; kv_b: (TOK,512)@(4096,512)^T
  k_gemm_bt<u16><<<dim3((NH * QHD) / 128, TOK / 128), 256, 0, stream>>>(qa_n, w_qb, qfull, TOK, NH * QHD, QL);
  k_gemm_bt<u16><<<dim3((NH * 256) / 128, TOK / 128), 256, 0, stream>>>(kv_n, w_kvb, kvfull, TOK, NH * 256, KVL);
  // pack (order matters for buffer reuse: pack_k reads ac before Qpk overwrites it)
  k_pack_k<<<(BB * NH * SS * QHD) / 256, 256, 0, stream>>>(kvfull, ac, pos, Kpk);
  k_pack_v<<<(BB * NH * VD * SS) / 256, 256, 0, stream>>>(kvfull, VT);
  k_pack_q<<<(BB * NH * SS * QHD) / 256, 256, 0, stream>>>(qfull, pos, Qpk);
  // attention
  k_attn<<<dim3(SS / 64, BB * NH), 256, 0, stream>>>(Qpk, Kpk, VT, attn_o);
  // output projection -> fp32 d_out
  k_gemm_bt<float><<<dim3(HID / 128, TOK / 128), 256, 0, stream>>>(attn_o, w_o, (float*)d_out, TOK, HID, NH * VD);
}

// Round 2
// 458.600 us; speedup vs baseline: 1.9361x; 1.9361x over previous
//
#include <hip/hip_runtime.h>
#include <hip/hip_bf16.h>
#include <stdint.h>
#include <type_traits>

#define DEVINL __device__ __forceinline__

typedef unsigned short u16;
typedef unsigned int   u32;
typedef short bf16x8 __attribute__((ext_vector_type(8)));
typedef float f32x4  __attribute__((ext_vector_type(4)));

// ---- problem constants ----
constexpr int BB   = 2,  SS  = 2048, HID = 2048, NH = 16;
constexpr int NOPE = 128, VD = 128, QHD = 192;
constexpr int QL   = 1536, KVL = 512;
constexpr int TOK  = BB * SS;            // 4096 tokens
constexpr int KVPAD = 640;               // kv_a rows 576 padded to 640
constexpr int NCOMB = QL + KVPAD;        // 2176 combined q_a+kv_a output dim
constexpr float SCALE     = 0.07216878364870322f;   // 192^-0.5
constexpr float LN1E4_32  = 0.28782313662425575f;   // ln(10000)/32

DEVINL float bf2f(u16 u) { union { u32 u; float f; } v; v.u = (u32)u << 16; return v.f; }
DEVINL u16 f2bf(float f) {
  union { float f; u32 u; } v; v.f = f;
  u32 r = v.u + 0x7fffu + ((v.u >> 16) & 1u);
  return (u16)(r >> 16);
}
DEVINL u32 pack2(float a, float b) { return (u32)f2bf(a) | ((u32)f2bf(b) << 16); }

DEVINL void gload_lds16(const u16* g, u16* l) {
  __builtin_amdgcn_global_load_lds(
      (const __attribute__((address_space(1))) void*)g,
      (__attribute__((address_space(3))) void*)l, 16, 0, 0);
}

// ---------------- fp32 -> bf16 conversion ----------------
__global__ void k_f2bf(const float* __restrict__ s, u16* __restrict__ d, int n) {
  int i = (blockIdx.x * 256 + threadIdx.x) * 4;
  if (i + 4 <= n) {
    float4 v = *(const float4*)(s + i);
    uint2 o; o.x = pack2(v.x, v.y); o.y = pack2(v.z, v.w);
    *(uint2*)(d + i) = o;
  } else {
    for (; i < n; ++i) d[i] = f2bf(s[i]);
  }
}

// convert with zero row padding (src: srows x cols, dst: drows x cols)
__global__ void k_f2bf_pad(const float* __restrict__ s, u16* __restrict__ d,
                           int srows, int cols, int drows) {
  int i = (blockIdx.x * 256 + threadIdx.x) * 4;
  int n = drows * cols;
  if (i + 4 > n) return;
  int row = i / cols;
  uint2 o;
  if (row < srows) {
    float4 v = *(const float4*)(s + i);
    o.x = pack2(v.x, v.y); o.y = pack2(v.z, v.w);
  } else {
    o.x = 0u; o.y = 0u;
  }
  *(uint2*)(d + i) = o;
}

// ---------------- NT GEMM: C[M][N] = A[M][K] * Bw[N][K]^T (bf16 in, OutT out) ----------------
template <typename OutT>
__global__ __launch_bounds__(256)
void k_gemm_bt(const u16* __restrict__ A, const u16* __restrict__ Bw,
               OutT* __restrict__ C, int M, int N, int K) {
  __shared__ u16 As[128 * 32];
  __shared__ u16 Bs[128 * 32];
  const int t = threadIdx.x;
  const int lane = t & 63, wave = t >> 6;
  const int wr = wave >> 1, wc = wave & 1;
  const int lq = lane & 15, lg = lane >> 4;
  const int m0 = blockIdx.y * 128, n0 = blockIdx.x * 128;

  f32x4 acc[4][4] = {};

  for (int k0 = 0; k0 < K; k0 += 32) {
#pragma unroll
    for (int i = 0; i < 2; ++i) {
      const int ebase = i * 256 + wave * 64;     // wave-uniform LDS base (16B units)
      const int e = ebase + lane;
      const int row = e >> 2, sl = e & 3;
      const int sg = sl ^ ((row ^ (row >> 2)) & 3);
      gload_lds16(A  + (size_t)(m0 + row) * K + (k0 + sg * 8), As + ebase * 8);
      gload_lds16(Bw + (size_t)(n0 + row) * K + (k0 + sg * 8), Bs + ebase * 8);
    }
    __syncthreads();

    bf16x8 af[4], bfv[4];
#pragma unroll
    for (int x = 0; x < 4; ++x) {
      int ra = wr * 64 + x * 16 + lq;
      af[x]  = *(const bf16x8*)(As + ra * 32 + (lg ^ ((ra ^ (ra >> 2)) & 3)) * 8);
      int rb = wc * 64 + x * 16 + lq;
      bfv[x] = *(const bf16x8*)(Bs + rb * 32 + (lg ^ ((rb ^ (rb >> 2)) & 3)) * 8);
    }
#pragma unroll
    for (int mi = 0; mi < 4; ++mi)
#pragma unroll
      for (int ni = 0; ni < 4; ++ni)
        acc[mi][ni] = __builtin_amdgcn_mfma_f32_16x16x32_bf16(af[mi], bfv[ni], acc[mi][ni], 0, 0, 0);
    __syncthreads();
  }

#pragma unroll
  for (int mi = 0; mi < 4; ++mi)
#pragma unroll
    for (int ni = 0; ni < 4; ++ni)
#pragma unroll
      for (int r = 0; r < 4; ++r) {
        int row = m0 + wr * 64 + mi * 16 + lg * 4 + r;
        int col = n0 + wc * 64 + ni * 16 + lq;
        float v = acc[mi][ni][r];
        if constexpr (std::is_same<OutT, float>::value)
          C[(size_t)row * N + col] = v;
        else
          C[(size_t)row * N + col] = f2bf(v);
      }
}

// ---------------- RMSNorm (row-wise, fp32 math, bf16 in/out) ----------------
__global__ __launch_bounds__(256)
void k_rmsnorm(const u16* __restrict__ x, const float* __restrict__ w,
               u16* __restrict__ y, int D, int xstride) {
  const int row = blockIdx.x;
  const u16* xr = x + (size_t)row * xstride;
  float ss = 0.f;
  for (int i = threadIdx.x; i < D; i += 256) { float v = bf2f(xr[i]); ss += v * v; }
#pragma unroll
  for (int o = 1; o < 64; o <<= 1) ss += __shfl_xor(ss, o);
  __shared__ float red[4];
  if ((threadIdx.x & 63) == 0) red[threadIdx.x >> 6] = ss;
  __syncthreads();
  float rs = rsqrtf((red[0] + red[1] + red[2] + red[3]) / (float)D + 1e-6f);
  u16* yr = y + (size_t)row * D;
  for (int i = threadIdx.x; i < D; i += 256) yr[i] = f2bf(bf2f(xr[i]) * rs * w[i]);
}

// ---------------- pack Q ----------------
__global__ void k_pack_q(const u16* __restrict__ qf, const int* __restrict__ pos,
                         u16* __restrict__ Qp) {
  int idx = blockIdx.x * 256 + threadIdx.x;
  int d = idx % QHD;
  int r0 = idx / QHD;
  int s = r0 % SS;
  int bh = r0 / SS;
  int b = bh >> 4, h = bh & 15;
  int token = b * SS + s;
  const u16* src = qf + (size_t)token * (NH * QHD) + h * QHD;
  u16 outv;
  if (d < NOPE) {
    outv = src[d];
  } else {
    int rr = d - NOPE;
    int j = rr & 31;
    float x0 = bf2f(src[NOPE + 2 * j]), x1 = bf2f(src[NOPE + 2 * j + 1]);
    float ang = (float)pos[b * SS + s] * __expf(-(float)j * LN1E4_32);
    float sn, c; sincosf(ang, &sn, &c);
    outv = f2bf(rr < 32 ? (x0 * c - x1 * sn) : (x1 * c + x0 * sn));
  }
  Qp[idx] = outv;
}

// ---------------- pack K ----------------
__global__ void k_pack_k(const u16* __restrict__ kvf, const u16* __restrict__ ac,
                         const int* __restrict__ pos, u16* __restrict__ Kp) {
  int idx = blockIdx.x * 256 + threadIdx.x;
  int d = idx % QHD;
  int r0 = idx / QHD;
  int s = r0 % SS;
  int bh = r0 / SS;
  int b = bh >> 4, h = bh & 15;
  int token = b * SS + s;
  u16 outv;
  if (d < NOPE) {
    outv = kvf[(size_t)token * (NH * 256) + h * 256 + d];
  } else {
    const u16* pe = ac + (size_t)token * NCOMB + (QL + KVL);  // k_pe cols (64)
    int rr = d - NOPE;
    int j = rr & 31;
    float x0 = bf2f(pe[2 * j]), x1 = bf2f(pe[2 * j + 1]);
    float ang = (float)pos[b * SS + s] * __expf(-(float)j * LN1E4_32);
    float sn, c; sincosf(ang, &sn, &c);
    outv = f2bf(rr < 32 ? (x0 * c - x1 * sn) : (x1 * c + x0 * sn));
  }
  Kp[idx] = outv;
}

// ---------------- pack V^T: (B,H,VD,S) ----------------
__global__ void k_pack_v(const u16* __restrict__ kvf, u16* __restrict__ VT) {
  int idx = blockIdx.x * 256 + threadIdx.x;
  int s = idx & (SS - 1);
  int r0 = idx >> 11;
  int v = r0 & 127;
  int bh = r0 >> 7;
  int b = bh >> 4, h = bh & 15;
  VT[idx] = kvf[(size_t)(b * SS + s) * (NH * 256) + h * 256 + NOPE + v];
}

// ---------------- causal flash attention, LDS-staged, 2-phase double-buffered ----------------
// grid (S/128, B*H), 8 waves/block; wave w owns q rows q0 = blk*128 + w*16.
// Per 32-key tile: K(32x192) + V^T(128x32) staged via global_load_lds with
// pre-swizzled SOURCE (rule #21: linear LDS dest, K: slot^=row&7, V: slot^=(row>>1)&3),
// ds_read applies the same XOR. 2-phase loop: STAGE(next) || compute(cur); vmcnt(0); s_barrier.
__global__ __launch_bounds__(512)
void k_attn(const u16* __restrict__ Qp, const u16* __restrict__ Kp,
            const u16* __restrict__ VT, u16* __restrict__ Oa) {
  const int bh = blockIdx.y;
  const int t = threadIdx.x, lane = t & 63, wave = t >> 6;
  const int lq = lane & 15, lg = lane >> 4;
  const int q0 = blockIdx.x * 128 + wave * 16;
  const size_t qkb = (size_t)bh * SS * QHD;
  const size_t vb  = (size_t)bh * VD * SS;

  __shared__ u16 Ks[2][32 * 192];     // 2 x 12 KB, row = key, 24 slots of 16B, swizzled
  __shared__ u16 Vs[2][128 * 32];     // 2 x 8 KB, row = v-dim, 4 slots of 16B, swizzled
  __shared__ u16 Pl[8][512];          // per-wave 16q x 32k bf16
  char* pl = (char*)&Pl[wave][0];
  const int swq = ((lq ^ (lq >> 2)) & 3) << 4;

  bf16x8 qf[6];
#pragma unroll
  for (int ch = 0; ch < 6; ++ch)
    qf[ch] = *(const bf16x8*)(Qp + qkb + (size_t)(q0 + lq) * QHD + ch * 32 + lg * 8);

  float m = -1e30f, lsum = 0.f;
  f32x4 o[8];
#pragma unroll
  for (int vc = 0; vc < 8; ++vc) o[vc] = (f32x4){0.f, 0.f, 0.f, 0.f};

  const int nt = (blockIdx.x + 1) * 4;     // 32-key tiles: keys [0, (blk+1)*128)

  // stage tile `tile` (kb = tile*32) into buffer `buf`
  auto stage = [&](int buf, int kb) {
    {   // K: 768 chunks of 16B; chunk c: row=c/24, slot=c%24; src slot pre-swizzled
      int c = t;
      int row = c / 24, sl = c % 24;
      gload_lds16(Kp + qkb + (size_t)(kb + row) * QHD + (sl ^ (row & 7)) * 8,
                  &Ks[buf][0] + c * 8);
    }
    if (t < 256) {
      int c = 512 + t;
      int row = c / 24, sl = c % 24;
      gload_lds16(Kp + qkb + (size_t)(kb + row) * QHD + (sl ^ (row & 7)) * 8,
                  &Ks[buf][0] + c * 8);
    }
    {   // V: 512 chunks; chunk t: row=t>>2, slot=t&3
      int row = t >> 2, sl = t & 3;
      gload_lds16(VT + vb + (size_t)row * SS + kb + (sl ^ ((row >> 1) & 3)) * 8,
                  &Vs[buf][0] + t * 8);
    }
  };

  stage(0, 0);
  asm volatile("s_waitcnt vmcnt(0)" ::: "memory");
  __builtin_amdgcn_s_barrier();

  for (int tt = 0; tt < nt; ++tt) {
    const int cur = tt & 1;
    if (tt + 1 < nt) stage(cur ^ 1, (tt + 1) * 32);
    const int kb = tt * 32;

    f32x4 slo = (f32x4){0.f, 0.f, 0.f, 0.f};
    f32x4 shi = (f32x4){0.f, 0.f, 0.f, 0.f};
#pragma unroll
    for (int ch = 0; ch < 6; ++ch) {
      const int ps = (ch * 4 + lg) ^ (lq & 7);      // (16+lq)&7 == lq&7
      bf16x8 klo = *(const bf16x8*)(&Ks[cur][0] + (lq * 24 + ps) * 8);
      bf16x8 khi = *(const bf16x8*)(&Ks[cur][0] + ((16 + lq) * 24 + ps) * 8);
      slo = __builtin_amdgcn_mfma_f32_16x16x32_bf16(klo, qf[ch], slo, 0, 0, 0);
      shi = __builtin_amdgcn_mfma_f32_16x16x32_bf16(khi, qf[ch], shi, 0, 0, 0);
    }

    const int qrow = q0 + lq;
    float mx = -1e30f;
#pragma unroll
    for (int r = 0; r < 4; ++r) {
      int klo = kb + lg * 4 + r;
      float v0 = (klo <= qrow)        ? slo[r] * SCALE : -1e30f;
      float v1 = ((klo + 16) <= qrow) ? shi[r] * SCALE : -1e30f;
      slo[r] = v0; shi[r] = v1;
      mx = fmaxf(mx, fmaxf(v0, v1));
    }
    mx = fmaxf(mx, __shfl_xor(mx, 16));
    mx = fmaxf(mx, __shfl_xor(mx, 32));
    float mnew = fmaxf(m, mx);
    float fac = __expf(m - mnew);
    float p0 = __expf(slo[0] - mnew), p1 = __expf(slo[1] - mnew);
    float p2 = __expf(slo[2] - mnew), p3 = __expf(slo[3] - mnew);
    float p4 = __expf(shi[0] - mnew), p5 = __expf(shi[1] - mnew);
    float p6 = __expf(shi[2] - mnew), p7 = __expf(shi[3] - mnew);
    float ps2 = ((p0 + p1) + (p2 + p3)) + ((p4 + p5) + (p6 + p7));
    ps2 += __shfl_xor(ps2, 16);
    ps2 += __shfl_xor(ps2, 32);
    lsum = lsum * fac + ps2;
    m = mnew;
#pragma unroll
    for (int vc = 0; vc < 8; ++vc) {
      o[vc][0] *= fac; o[vc][1] *= fac; o[vc][2] *= fac; o[vc][3] *= fac;
    }
    *(u32*)(pl + lq * 64 + ((8 * lg)          ^ swq)) = pack2(p0, p1);
    *(u32*)(pl + lq * 64 + ((8 * lg + 4)      ^ swq)) = pack2(p2, p3);
    *(u32*)(pl + lq * 64 + ((32 + 8 * lg)     ^ swq)) = pack2(p4, p5);
    *(u32*)(pl + lq * 64 + ((32 + 8 * lg + 4) ^ swq)) = pack2(p6, p7);
    bf16x8 pf = *(const bf16x8*)(pl + lq * 64 + ((16 * lg) ^ swq));
#pragma unroll
    for (int vc = 0; vc < 8; ++vc) {
      const int rv = vc * 16 + lq;
      const int psv = lg ^ ((rv >> 1) & 3);
      bf16x8 vf = *(const bf16x8*)(&Vs[cur][0] + rv * 32 + psv * 8);
      o[vc] = __builtin_amdgcn_mfma_f32_16x16x32_bf16(vf, pf, o[vc], 0, 0, 0);
    }

    asm volatile("s_waitcnt vmcnt(0)" ::: "memory");
    __builtin_amdgcn_s_barrier();
  }

  const float inv = 1.0f / lsum;
  const int b = bh >> 4, h = bh & 15;
  u16* orow = Oa + (size_t)(b * SS + q0 + lq) * (NH * VD) + h * VD;
#pragma unroll
  for (int vc = 0; vc < 8; ++vc)
#pragma unroll
    for (int r = 0; r < 4; ++r)
      orow[vc * 16 + lg * 4 + r] = f2bf(o[vc][r] * inv);
}

// ---------------- host launch ----------------
extern "C" void kernel_launch(void* const* d_in, const int* in_sizes, int n_in,
                              void* d_out, int out_size, void* d_ws, size_t ws_size,
                              hipStream_t stream) {
  (void)in_sizes; (void)n_in; (void)out_size; (void)ws_size;
  const float* hidden  = (const float*)d_in[0];
  /* d_in[1] attention_mask: exactly triu(-1e9) causal -> applied analytically */
  const int*   pos     = (const int*)d_in[2];
  const float* q_a_w   = (const float*)d_in[3];
  const float* q_a_ln  = (const float*)d_in[4];
  const float* q_b_w   = (const float*)d_in[5];
  const float* kv_a_w  = (const float*)d_in[6];
  const float* kv_a_ln = (const float*)d_in[7];
  const float* kv_b_w  = (const float*)d_in[8];
  const float* o_w     = (const float*)d_in[9];

  char* ws = (char*)d_ws;
  u16* hid_bf = (u16*)(ws + 0);          // 16,777,216   (later reused as VT)
  u16* VT     = (u16*)(ws + 0);
  u16* w_comb = (u16*)(ws + 16777216);   //  8,912,896
  u16* w_qb   = (u16*)(ws + 25690112);   //  9,437,184
  u16* w_kvb  = (u16*)(ws + 35127296);   //  4,194,304
  u16* w_o    = (u16*)(ws + 39321600);   //  8,388,608
  u16* ac     = (u16*)(ws + 47710208);   // 17,825,792  (TOK x 2176)
  u16* qa_n   = (u16*)(ws + 65536000);   // 12,582,912
  u16* Qpk    = (u16*)(ws + 47710208);   // 25,165,824  (over ac+qa_n, after pack_k)
  u16* kv_n   = (u16*)(ws + 78118912);   //  4,194,304
  u16* qfull  = (u16*)(ws + 82313216);   // 25,165,824
  u16* attn_o = (u16*)(ws + 82313216);   // 16,777,216  (over qfull, after pack_q)
  u16* kvfull = (u16*)(ws + 107479040);  // 33,554,432
  u16* Kpk    = (u16*)(ws + 141033472);  // 25,165,824  -> total 166,199,296 B

  // fp32 -> bf16 conversions
  k_f2bf<<<(TOK * HID) / 1024, 256, 0, stream>>>(hidden, hid_bf, TOK * HID);
  k_f2bf<<<(QL * HID) / 1024, 256, 0, stream>>>(q_a_w, w_comb, QL * HID);
  k_f2bf_pad<<<(KVPAD * HID) / 1024, 256, 0, stream>>>(kv_a_w, w_comb + QL * HID, KVL + 64, HID, KVPAD);
  k_f2bf<<<(NH * QHD * QL) / 1024, 256, 0, stream>>>(q_b_w, w_qb, NH * QHD * QL);
  k_f2bf<<<(NH * 256 * KVL) / 1024, 256, 0, stream>>>(kv_b_w, w_kvb, NH * 256 * KVL);
  k_f2bf<<<(HID * NH * VD) / 1024, 256, 0, stream>>>(o_w, w_o, HID * NH * VD);

  // q_a + kv_a combined: (TOK,2048) @ (2176,2048)^T
  k_gemm_bt<u16><<<dim3(NCOMB / 128, TOK / 128), 256, 0, stream>>>(hid_bf, w_comb, ac, TOK, NCOMB, HID);
  // RMS norms
  k_rmsnorm<<<TOK, 256, 0, stream>>>(ac,      q_a_ln,  qa_n, QL,  NCOMB);
  k_rmsnorm<<<TOK, 256, 0, stream>>>(ac + QL, kv_a_ln, kv_n, KVL, NCOMB);
  // q_b / kv_b
  k_gemm_bt<u16><<<dim3((NH * QHD) / 128, TOK / 128), 256, 0, stream>>>(qa_n, w_qb, qfull, TOK, NH * QHD, QL);
  k_gemm_bt<u16><<<dim3((NH * 256) / 128, TOK / 128), 256, 0, stream>>>(kv_n, w_kvb, kvfull, TOK, NH * 256, KVL);
  // pack (order matters: pack_k reads ac before Qpk overwrites it)
  k_pack_k<<<(BB * NH * SS * QHD) / 256, 256, 0, stream>>>(kvfull, ac, pos, Kpk);
  k_pack_v<<<(BB * NH * VD * SS) / 256, 256, 0, stream>>>(kvfull, VT);
  k_pack_q<<<(BB * NH * SS * QHD) / 256, 256, 0, stream>>>(qfull, pos, Qpk);
  // attention: grid (S/128, B*H), 8 waves
  k_attn<<<dim3(SS / 128, BB * NH), 512, 0, stream>>>(Qpk, Kpk, VT, attn_o);
  // output projection -> fp32 d_out
  k_gemm_bt<float><<<dim3(HID / 128, TOK / 128), 256, 0, stream>>>(attn_o, w_o, (float*)d_out, TOK, HID, NH * VD);
}

// Round 3
// 454.766 us; speedup vs baseline: 1.9524x; 1.0084x over previous
//
#include <hip/hip_runtime.h>
#include <hip/hip_bf16.h>
#include <stdint.h>
#include <type_traits>

#define DEVINL __device__ __forceinline__

typedef unsigned short u16;
typedef unsigned int   u32;
typedef short bf16x8 __attribute__((ext_vector_type(8)));
typedef float f32x4  __attribute__((ext_vector_type(4)));

// ---- problem constants ----
constexpr int BB   = 2,  SS  = 2048, HID = 2048, NH = 16;
constexpr int NOPE = 128, VD = 128, QHD = 192;
constexpr int QL   = 1536, KVL = 512;
constexpr int TOK  = BB * SS;            // 4096 tokens
constexpr int NCOMB = 2176;              // ac row stride (q 1536 + ckv 512 + pe 64 + 64 slack)
constexpr int NREAL = 2112;              // real combined output cols (1536+512+64)
constexpr float SCALE     = 0.07216878364870322f;   // 192^-0.5
constexpr float LN1E4_32  = 0.28782313662425575f;   // ln(10000)/32

DEVINL float bf2f(u16 u) { union { u32 u; float f; } v; v.u = (u32)u << 16; return v.f; }
DEVINL u16 f2bf(float f) {
  union { float f; u32 u; } v; v.f = f;
  u32 r = v.u + 0x7fffu + ((v.u >> 16) & 1u);
  return (u16)(r >> 16);
}
DEVINL u32 pack2(float a, float b) { return (u32)f2bf(a) | ((u32)f2bf(b) << 16); }

DEVINL void gload_lds16(const u16* g, u16* l) {
  __builtin_amdgcn_global_load_lds(
      (const __attribute__((address_space(1))) void*)g,
      (__attribute__((address_space(3))) void*)l, 16, 0, 0);
}

// ---------------- fp32 -> bf16 conversion ----------------
__global__ void k_f2bf(const float* __restrict__ s, u16* __restrict__ d, int n) {
  int i = (blockIdx.x * 256 + threadIdx.x) * 4;
  if (i + 4 <= n) {
    float4 v = *(const float4*)(s + i);
    uint2 o; o.x = pack2(v.x, v.y); o.y = pack2(v.z, v.w);
    *(uint2*)(d + i) = o;
  } else {
    for (; i < n; ++i) d[i] = f2bf(s[i]);
  }
}

// ---------------- 256x256 8-phase NT GEMM: C[M][Nld] = A[M][K] * Bw[N][K]^T ----------------
// 512 thr / 8 waves (2M x 4N), per-wave 128x64 C, BK=64, 2-dbuf 128KB LDS.
// T2: slot ^= row&7 swizzle (pre-swizzled global source, linear LDS dest, same XOR on read).
// T3+T4: ds_reads front-loaded P0/P1; staging calendar T+1.Bhi@P0, T+2.{Alo,Ahi}@P2,
// T+2.Blo@P3 -> exactly 3 half-tiles (6 loads) in flight at each K-boundary -> vmcnt(6).
// T5: setprio(1) around each 16-MFMA cluster.
template <typename OutT>
__global__ __launch_bounds__(512, 2)
void k_gemm256(const u16* __restrict__ A, const u16* __restrict__ Bw,
               OutT* __restrict__ C, int Nld, int Ncap, int K) {
  __shared__ u16 SA[2][2][128 * 64];   // [dbuf][Mhalf][row*64 + swz-col]
  __shared__ u16 SB[2][2][128 * 64];   // [dbuf][Nhalf][...]
  const int t = threadIdx.x;
  const int lane = t & 63, wave = t >> 6;
  const int wr = wave >> 2, wc = wave & 3;
  const int lq = lane & 15, lg = lane >> 4;
  const int m0 = blockIdx.y * 256, n0 = blockIdx.x * 256;
  const int NT = K >> 6;

  const int r0 = t >> 3;                         // staged row (chunk0); chunk1 = row+64
  const int cs = ((t & 7) ^ (r0 & 7)) * 8;       // pre-swizzled source col (elems)

  auto stageA = [&](int d, int h, int kt) {
    const u16* g = A + (size_t)(m0 + h * 128) * K + kt * 64;
    u16* l = &SA[d][h][0];
    gload_lds16(g + (size_t)r0 * K + cs, l + t * 8);
    gload_lds16(g + (size_t)(r0 + 64) * K + cs, l + (t + 512) * 8);
  };
  auto stageB = [&](int d, int h, int kt) {
    const u16* g = Bw + (size_t)(n0 + h * 128) * K + kt * 64;
    u16* l = &SB[d][h][0];
    gload_lds16(g + (size_t)r0 * K + cs, l + t * 8);
    gload_lds16(g + (size_t)(r0 + 64) * K + cs, l + (t + 512) * 8);
  };
  auto rdA = [&](int d, int m, int k) -> bf16x8 {
    int row = m * 16 + lq;
    return *(const bf16x8*)(&SA[d][wr][0] + row * 64 + (((k * 4 + lg) ^ (row & 7)) * 8));
  };
  auto rdB = [&](int d, int n, int k) -> bf16x8 {
    int row = (wc & 1) * 64 + n * 16 + lq;
    return *(const bf16x8*)(&SB[d][wc >> 1][0] + row * 64 + (((k * 4 + lg) ^ (row & 7)) * 8));
  };

  f32x4 acc[8][4] = {};
  bf16x8 a[8][2], b[4][2];

  // prologue: T0 fully, T1 first 3 halves (Alo,Ahi,Blo)
  stageA(0, 0, 0); stageA(0, 1, 0); stageB(0, 0, 0); stageB(0, 1, 0);
  if (NT > 1) { stageA(1, 0, 1); stageA(1, 1, 1); stageB(1, 0, 1); }
  asm volatile("s_waitcnt vmcnt(6)" ::: "memory");
  __builtin_amdgcn_s_barrier();

  for (int T = 0; T < NT; ++T) {
    const int d = T & 1;
    // ---- P0: read a[0..3][*], b[0..1][*]; stage T+1.Bhi
#pragma unroll
    for (int m = 0; m < 4; ++m) { a[m][0] = rdA(d, m, 0); a[m][1] = rdA(d, m, 1); }
#pragma unroll
    for (int n = 0; n < 2; ++n) { b[n][0] = rdB(d, n, 0); b[n][1] = rdB(d, n, 1); }
    if (T + 1 < NT) stageB(d ^ 1, 1, T + 1);
    asm volatile("s_waitcnt lgkmcnt(8)" ::: "memory");
    __builtin_amdgcn_s_barrier();
    asm volatile("s_waitcnt lgkmcnt(0)" ::: "memory");
    __builtin_amdgcn_s_setprio(1);
#pragma unroll
    for (int m = 0; m < 4; ++m)
#pragma unroll
      for (int n = 0; n < 2; ++n) {
        acc[m][n] = __builtin_amdgcn_mfma_f32_16x16x32_bf16(a[m][0], b[n][0], acc[m][n], 0, 0, 0);
        acc[m][n] = __builtin_amdgcn_mfma_f32_16x16x32_bf16(a[m][1], b[n][1], acc[m][n], 0, 0, 0);
      }
    __builtin_amdgcn_s_setprio(0);
    __builtin_amdgcn_s_barrier();
    // ---- P1: read a[4..7][*], b[2..3][*]
#pragma unroll
    for (int m = 4; m < 8; ++m) { a[m][0] = rdA(d, m, 0); a[m][1] = rdA(d, m, 1); }
#pragma unroll
    for (int n = 2; n < 4; ++n) { b[n][0] = rdB(d, n, 0); b[n][1] = rdB(d, n, 1); }
    asm volatile("s_waitcnt lgkmcnt(8)" ::: "memory");
    __builtin_amdgcn_s_barrier();
    asm volatile("s_waitcnt lgkmcnt(0)" ::: "memory");
    __builtin_amdgcn_s_setprio(1);
#pragma unroll
    for (int m = 4; m < 8; ++m)
#pragma unroll
      for (int n = 0; n < 2; ++n) {
        acc[m][n] = __builtin_amdgcn_mfma_f32_16x16x32_bf16(a[m][0], b[n][0], acc[m][n], 0, 0, 0);
        acc[m][n] = __builtin_amdgcn_mfma_f32_16x16x32_bf16(a[m][1], b[n][1], acc[m][n], 0, 0, 0);
      }
    __builtin_amdgcn_s_setprio(0);
    __builtin_amdgcn_s_barrier();
    // ---- P2: MFMA m0-3 x n2-3 (regs); stage T+2.Alo,Ahi (reads of SA[d] all done)
    if (T + 2 < NT) { stageA(d, 0, T + 2); stageA(d, 1, T + 2); }
    __builtin_amdgcn_s_barrier();
    __builtin_amdgcn_s_setprio(1);
#pragma unroll
    for (int m = 0; m < 4; ++m)
#pragma unroll
      for (int n = 2; n < 4; ++n) {
        acc[m][n] = __builtin_amdgcn_mfma_f32_16x16x32_bf16(a[m][0], b[n][0], acc[m][n], 0, 0, 0);
        acc[m][n] = __builtin_amdgcn_mfma_f32_16x16x32_bf16(a[m][1], b[n][1], acc[m][n], 0, 0, 0);
      }
    __builtin_amdgcn_s_setprio(0);
    __builtin_amdgcn_s_barrier();
    // ---- P3: MFMA m4-7 x n2-3; stage T+2.Blo; boundary vmcnt
    if (T + 2 < NT) stageB(d, 0, T + 2);
    __builtin_amdgcn_s_barrier();
    __builtin_amdgcn_s_setprio(1);
#pragma unroll
    for (int m = 4; m < 8; ++m)
#pragma unroll
      for (int n = 2; n < 4; ++n) {
        acc[m][n] = __builtin_amdgcn_mfma_f32_16x16x32_bf16(a[m][0], b[n][0], acc[m][n], 0, 0, 0);
        acc[m][n] = __builtin_amdgcn_mfma_f32_16x16x32_bf16(a[m][1], b[n][1], acc[m][n], 0, 0, 0);
      }
    __builtin_amdgcn_s_setprio(0);
    if (T + 2 < NT)      asm volatile("s_waitcnt vmcnt(6)" ::: "memory");
    else if (T + 1 < NT) asm volatile("s_waitcnt vmcnt(0)" ::: "memory");
    __builtin_amdgcn_s_barrier();
  }

  // epilogue: guarded C write
#pragma unroll
  for (int m = 0; m < 8; ++m)
#pragma unroll
    for (int n = 0; n < 4; ++n) {
      const int col = n0 + wc * 64 + n * 16 + lq;
      if (col < Ncap) {
        const int row = m0 + wr * 128 + m * 16 + lg * 4;
#pragma unroll
        for (int r = 0; r < 4; ++r) {
          float v = acc[m][n][r];
          if constexpr (std::is_same<OutT, float>::value)
            C[(size_t)(row + r) * Nld + col] = v;
          else
            C[(size_t)(row + r) * Nld + col] = f2bf(v);
        }
      }
    }
}

// ---------------- RMSNorm (row-wise, fp32 math, bf16 in/out) ----------------
__global__ __launch_bounds__(256)
void k_rmsnorm(const u16* __restrict__ x, const float* __restrict__ w,
               u16* __restrict__ y, int D, int xstride) {
  const int row = blockIdx.x;
  const u16* xr = x + (size_t)row * xstride;
  float ss = 0.f;
  for (int i = threadIdx.x; i < D; i += 256) { float v = bf2f(xr[i]); ss += v * v; }
#pragma unroll
  for (int o = 1; o < 64; o <<= 1) ss += __shfl_xor(ss, o);
  __shared__ float red[4];
  if ((threadIdx.x & 63) == 0) red[threadIdx.x >> 6] = ss;
  __syncthreads();
  float rs = rsqrtf((red[0] + red[1] + red[2] + red[3]) / (float)D + 1e-6f);
  u16* yr = y + (size_t)row * D;
  for (int i = threadIdx.x; i < D; i += 256) yr[i] = f2bf(bf2f(xr[i]) * rs * w[i]);
}

// ---------------- pack Q ----------------
__global__ void k_pack_q(const u16* __restrict__ qf, const int* __restrict__ pos,
                         u16* __restrict__ Qp) {
  int idx = blockIdx.x * 256 + threadIdx.x;
  int d = idx % QHD;
  int r0 = idx / QHD;
  int s = r0 % SS;
  int bh = r0 / SS;
  int b = bh >> 4, h = bh & 15;
  int token = b * SS + s;
  const u16* src = qf + (size_t)token * (NH * QHD) + h * QHD;
  u16 outv;
  if (d < NOPE) {
    outv = src[d];
  } else {
    int rr = d - NOPE;
    int j = rr & 31;
    float x0 = bf2f(src[NOPE + 2 * j]), x1 = bf2f(src[NOPE + 2 * j + 1]);
    float ang = (float)pos[b * SS + s] * __expf(-(float)j * LN1E4_32);
    float sn, c; sincosf(ang, &sn, &c);
    outv = f2bf(rr < 32 ? (x0 * c - x1 * sn) : (x1 * c + x0 * sn));
  }
  Qp[idx] = outv;
}

// ---------------- pack K ----------------
__global__ void k_pack_k(const u16* __restrict__ kvf, const u16* __restrict__ ac,
                         const int* __restrict__ pos, u16* __restrict__ Kp) {
  int idx = blockIdx.x * 256 + threadIdx.x;
  int d = idx % QHD;
  int r0 = idx / QHD;
  int s = r0 % SS;
  int bh = r0 / SS;
  int b = bh >> 4, h = bh & 15;
  int token = b * SS + s;
  u16 outv;
  if (d < NOPE) {
    outv = kvf[(size_t)token * (NH * 256) + h * 256 + d];
  } else {
    const u16* pe = ac + (size_t)token * NCOMB + (QL + KVL);  // k_pe cols (64)
    int rr = d - NOPE;
    int j = rr & 31;
    float x0 = bf2f(pe[2 * j]), x1 = bf2f(pe[2 * j + 1]);
    float ang = (float)pos[b * SS + s] * __expf(-(float)j * LN1E4_32);
    float sn, c; sincosf(ang, &sn, &c);
    outv = f2bf(rr < 32 ? (x0 * c - x1 * sn) : (x1 * c + x0 * sn));
  }
  Kp[idx] = outv;
}

// ---------------- pack V^T: (B,H,VD,S) ----------------
__global__ void k_pack_v(const u16* __restrict__ kvf, u16* __restrict__ VT) {
  int idx = blockIdx.x * 256 + threadIdx.x;
  int s = idx & (SS - 1);
  int r0 = idx >> 11;
  int v = r0 & 127;
  int bh = r0 >> 7;
  int b = bh >> 4, h = bh & 15;
  VT[idx] = kvf[(size_t)(b * SS + s) * (NH * 256) + h * 256 + NOPE + v];
}

// ---------------- causal flash attention, LDS-staged, 2-phase double-buffered ----------------
__global__ __launch_bounds__(512)
void k_attn(const u16* __restrict__ Qp, const u16* __restrict__ Kp,
            const u16* __restrict__ VT, u16* __restrict__ Oa) {
  const int bh = blockIdx.y;
  const int t = threadIdx.x, lane = t & 63, wave = t >> 6;
  const int lq = lane & 15, lg = lane >> 4;
  const int q0 = blockIdx.x * 128 + wave * 16;
  const size_t qkb = (size_t)bh * SS * QHD;
  const size_t vb  = (size_t)bh * VD * SS;

  __shared__ u16 Ks[2][32 * 192];     // row = key, 24 slots of 16B, swizzled
  __shared__ u16 Vs[2][128 * 32];     // row = v-dim, 4 slots of 16B, swizzled
  __shared__ u16 Pl[8][512];          // per-wave 16q x 32k bf16
  char* pl = (char*)&Pl[wave][0];
  const int swq = ((lq ^ (lq >> 2)) & 3) << 4;

  bf16x8 qf[6];
#pragma unroll
  for (int ch = 0; ch < 6; ++ch)
    qf[ch] = *(const bf16x8*)(Qp + qkb + (size_t)(q0 + lq) * QHD + ch * 32 + lg * 8);

  float m = -1e30f, lsum = 0.f;
  f32x4 o[8];
#pragma unroll
  for (int vc = 0; vc < 8; ++vc) o[vc] = (f32x4){0.f, 0.f, 0.f, 0.f};

  const int nt = (blockIdx.x + 1) * 4;     // 32-key tiles: keys [0, (blk+1)*128)

  auto stage = [&](int buf, int kb) {
    {
      int c = t;
      int row = c / 24, sl = c % 24;
      gload_lds16(Kp + qkb + (size_t)(kb + row) * QHD + (sl ^ (row & 7)) * 8,
                  &Ks[buf][0] + c * 8);
    }
    if (t < 256) {
      int c = 512 + t;
      int row = c / 24, sl = c % 24;
      gload_lds16(Kp + qkb + (size_t)(kb + row) * QHD + (sl ^ (row & 7)) * 8,
                  &Ks[buf][0] + c * 8);
    }
    {
      int row = t >> 2, sl = t & 3;
      gload_lds16(VT + vb + (size_t)row * SS + kb + (sl ^ ((row >> 1) & 3)) * 8,
                  &Vs[buf][0] + t * 8);
    }
  };

  stage(0, 0);
  asm volatile("s_waitcnt vmcnt(0)" ::: "memory");
  __builtin_amdgcn_s_barrier();

  for (int tt = 0; tt < nt; ++tt) {
    const int cur = tt & 1;
    if (tt + 1 < nt) stage(cur ^ 1, (tt + 1) * 32);
    const int kb = tt * 32;

    f32x4 slo = (f32x4){0.f, 0.f, 0.f, 0.f};
    f32x4 shi = (f32x4){0.f, 0.f, 0.f, 0.f};
#pragma unroll
    for (int ch = 0; ch < 6; ++ch) {
      const int ps = (ch * 4 + lg) ^ (lq & 7);
      bf16x8 klo = *(const bf16x8*)(&Ks[cur][0] + (lq * 24 + ps) * 8);
      bf16x8 khi = *(const bf16x8*)(&Ks[cur][0] + ((16 + lq) * 24 + ps) * 8);
      slo = __builtin_amdgcn_mfma_f32_16x16x32_bf16(klo, qf[ch], slo, 0, 0, 0);
      shi = __builtin_amdgcn_mfma_f32_16x16x32_bf16(khi, qf[ch], shi, 0, 0, 0);
    }

    const int qrow = q0 + lq;
    float mx = -1e30f;
#pragma unroll
    for (int r = 0; r < 4; ++r) {
      int klo = kb + lg * 4 + r;
      float v0 = (klo <= qrow)        ? slo[r] * SCALE : -1e30f;
      float v1 = ((klo + 16) <= qrow) ? shi[r] * SCALE : -1e30f;
      slo[r] = v0; shi[r] = v1;
      mx = fmaxf(mx, fmaxf(v0, v1));
    }
    mx = fmaxf(mx, __shfl_xor(mx, 16));
    mx = fmaxf(mx, __shfl_xor(mx, 32));
    float mnew = fmaxf(m, mx);
    float fac = __expf(m - mnew);
    float p0 = __expf(slo[0] - mnew), p1 = __expf(slo[1] - mnew);
    float p2 = __expf(slo[2] - mnew), p3 = __expf(slo[3] - mnew);
    float p4 = __expf(shi[0] - mnew), p5 = __expf(shi[1] - mnew);
    float p6 = __expf(shi[2] - mnew), p7 = __expf(shi[3] - mnew);
    float ps2 = ((p0 + p1) + (p2 + p3)) + ((p4 + p5) + (p6 + p7));
    ps2 += __shfl_xor(ps2, 16);
    ps2 += __shfl_xor(ps2, 32);
    lsum = lsum * fac + ps2;
    m = mnew;
#pragma unroll
    for (int vc = 0; vc < 8; ++vc) {
      o[vc][0] *= fac; o[vc][1] *= fac; o[vc][2] *= fac; o[vc][3] *= fac;
    }
    *(u32*)(pl + lq * 64 + ((8 * lg)          ^ swq)) = pack2(p0, p1);
    *(u32*)(pl + lq * 64 + ((8 * lg + 4)      ^ swq)) = pack2(p2, p3);
    *(u32*)(pl + lq * 64 + ((32 + 8 * lg)     ^ swq)) = pack2(p4, p5);
    *(u32*)(pl + lq * 64 + ((32 + 8 * lg + 4) ^ swq)) = pack2(p6, p7);
    bf16x8 pf = *(const bf16x8*)(pl + lq * 64 + ((16 * lg) ^ swq));
#pragma unroll
    for (int vc = 0; vc < 8; ++vc) {
      const int rv = vc * 16 + lq;
      const int psv = lg ^ ((rv >> 1) & 3);
      bf16x8 vf = *(const bf16x8*)(&Vs[cur][0] + rv * 32 + psv * 8);
      o[vc] = __builtin_amdgcn_mfma_f32_16x16x32_bf16(vf, pf, o[vc], 0, 0, 0);
    }

    asm volatile("s_waitcnt vmcnt(0)" ::: "memory");
    __builtin_amdgcn_s_barrier();
  }

  const float inv = 1.0f / lsum;
  const int b = bh >> 4, h = bh & 15;
  u16* orow = Oa + (size_t)(b * SS + q0 + lq) * (NH * VD) + h * VD;
#pragma unroll
  for (int vc = 0; vc < 8; ++vc)
#pragma unroll
    for (int r = 0; r < 4; ++r)
      orow[vc * 16 + lg * 4 + r] = f2bf(o[vc][r] * inv);
}

// ---------------- host launch ----------------
extern "C" void kernel_launch(void* const* d_in, const int* in_sizes, int n_in,
                              void* d_out, int out_size, void* d_ws, size_t ws_size,
                              hipStream_t stream) {
  (void)in_sizes; (void)n_in; (void)out_size; (void)ws_size;
  const float* hidden  = (const float*)d_in[0];
  /* d_in[1] attention_mask: exactly triu(-1e9) causal -> applied analytically */
  const int*   pos     = (const int*)d_in[2];
  const float* q_a_w   = (const float*)d_in[3];
  const float* q_a_ln  = (const float*)d_in[4];
  const float* q_b_w   = (const float*)d_in[5];
  const float* kv_a_w  = (const float*)d_in[6];
  const float* kv_a_ln = (const float*)d_in[7];
  const float* kv_b_w  = (const float*)d_in[8];
  const float* o_w     = (const float*)d_in[9];

  char* ws = (char*)d_ws;
  u16* hid_bf = (u16*)(ws + 0);          // 16,777,216   (later reused as VT)
  u16* VT     = (u16*)(ws + 0);
  u16* w_comb = (u16*)(ws + 16777216);   //  slot 8,912,896 (2112 rows used; GEMM1 over-reads into w_qb, guarded)
  u16* w_qb   = (u16*)(ws + 25690112);   //  9,437,184
  u16* w_kvb  = (u16*)(ws + 35127296);   //  4,194,304
  u16* w_o    = (u16*)(ws + 39321600);   //  8,388,608
  u16* ac     = (u16*)(ws + 47710208);   // 17,825,792  (TOK x 2176)
  u16* qa_n   = (u16*)(ws + 65536000);   // 12,582,912
  u16* Qpk    = (u16*)(ws + 47710208);   // 25,165,824  (over ac+qa_n, after pack_k)
  u16* kv_n   = (u16*)(ws + 78118912);   //  4,194,304
  u16* qfull  = (u16*)(ws + 82313216);   // 25,165,824
  u16* attn_o = (u16*)(ws + 82313216);   // 16,777,216  (over qfull, after pack_q)
  u16* kvfull = (u16*)(ws + 107479040);  // 33,554,432
  u16* Kpk    = (u16*)(ws + 141033472);  // 25,165,824  -> total 166,199,296 B

  // fp32 -> bf16 conversions (q_a rows 0..1535, kv_a rows 1536..2111 of w_comb)
  k_f2bf<<<(TOK * HID) / 1024, 256, 0, stream>>>(hidden, hid_bf, TOK * HID);
  k_f2bf<<<(QL * HID) / 1024, 256, 0, stream>>>(q_a_w, w_comb, QL * HID);
  k_f2bf<<<((KVL + 64) * HID) / 1024, 256, 0, stream>>>(kv_a_w, w_comb + QL * HID, (KVL + 64) * HID);
  k_f2bf<<<(NH * QHD * QL) / 1024, 256, 0, stream>>>(q_b_w, w_qb, NH * QHD * QL);
  k_f2bf<<<(NH * 256 * KVL) / 1024, 256, 0, stream>>>(kv_b_w, w_kvb, NH * 256 * KVL);
  k_f2bf<<<(HID * NH * VD) / 1024, 256, 0, stream>>>(o_w, w_o, HID * NH * VD);

  // q_a + kv_a combined: (TOK,2048) @ (2112,2048)^T  [logical N=2304, guarded]
  k_gemm256<u16><<<dim3(9, TOK / 256), 512, 0, stream>>>(hid_bf, w_comb, ac, NCOMB, NREAL, HID);
  // RMS norms
  k_rmsnorm<<<TOK, 256, 0, stream>>>(ac,      q_a_ln,  qa_n, QL,  NCOMB);
  k_rmsnorm<<<TOK, 256, 0, stream>>>(ac + QL, kv_a_ln, kv_n, KVL, NCOMB);
  // q_b: (TOK,1536)@(3072,1536)^T ; kv_b: (TOK,512)@(4096,512)^T
  k_gemm256<u16><<<dim3(12, TOK / 256), 512, 0, stream>>>(qa_n, w_qb, qfull, NH * QHD, NH * QHD, QL);
  k_gemm256<u16><<<dim3(16, TOK / 256), 512, 0, stream>>>(kv_n, w_kvb, kvfull, NH * 256, NH * 256, KVL);
  // pack (order matters: pack_k reads ac before Qpk overwrites it)
  k_pack_k<<<(BB * NH * SS * QHD) / 256, 256, 0, stream>>>(kvfull, ac, pos, Kpk);
  k_pack_v<<<(BB * NH * VD * SS) / 256, 256, 0, stream>>>(kvfull, VT);
  k_pack_q<<<(BB * NH * SS * QHD) / 256, 256, 0, stream>>>(qfull, pos, Qpk);
  // attention: grid (S/128, B*H), 8 waves
  k_attn<<<dim3(SS / 128, BB * NH), 512, 0, stream>>>(Qpk, Kpk, VT, attn_o);
  // output projection -> fp32 d_out
  k_gemm256<float><<<dim3(8, TOK / 256), 512, 0, stream>>>(attn_o, w_o, (float*)d_out, HID, HID, NH * VD);
}

// Round 4
// 422.492 us; speedup vs baseline: 2.1016x; 1.0764x over previous
//
#include <hip/hip_runtime.h>
#include <hip/hip_bf16.h>
#include <stdint.h>
#include <type_traits>

#define DEVINL __device__ __forceinline__

typedef unsigned short u16;
typedef unsigned int   u32;
typedef short bf16x8 __attribute__((ext_vector_type(8)));
typedef float f32x4  __attribute__((ext_vector_type(4)));

// ---- problem constants ----
constexpr int BB   = 2,  SS  = 2048, HID = 2048, NH = 16;
constexpr int NOPE = 128, VD = 128, QHD = 192;
constexpr int QL   = 1536, KVL = 512;
constexpr int TOK  = BB * SS;            // 4096 tokens
constexpr int NCOMB = 2176;              // ac row stride
constexpr int NREAL = 2112;              // real combined output cols (1536+512+64)
constexpr float SCALE     = 0.07216878364870322f;   // 192^-0.5
constexpr float SCALE2    = 0.10412907368573824f;   // SCALE * log2(e)
constexpr float LN1E4_32  = 0.28782313662425575f;   // ln(10000)/32

DEVINL float bf2f(u16 u) { union { u32 u; float f; } v; v.u = (u32)u << 16; return v.f; }
DEVINL u16 f2bf(float f) {
  union { float f; u32 u; } v; v.f = f;
  u32 r = v.u + 0x7fffu + ((v.u >> 16) & 1u);
  return (u16)(r >> 16);
}
DEVINL u32 pack2(float a, float b) { return (u32)f2bf(a) | ((u32)f2bf(b) << 16); }

DEVINL float fexp2(float x) {
#if __has_builtin(__builtin_amdgcn_exp2f)
  return __builtin_amdgcn_exp2f(x);
#else
  return __expf(x * 0.6931471805599453f);
#endif
}

DEVINL void gload_lds16(const u16* g, u16* l) {
  __builtin_amdgcn_global_load_lds(
      (const __attribute__((address_space(1))) void*)g,
      (__attribute__((address_space(3))) void*)l, 16, 0, 0);
}

// ---------------- fp32 -> bf16 conversion ----------------
__global__ void k_f2bf(const float* __restrict__ s, u16* __restrict__ d, int n) {
  int i = (blockIdx.x * 256 + threadIdx.x) * 4;
  if (i + 4 <= n) {
    float4 v = *(const float4*)(s + i);
    uint2 o; o.x = pack2(v.x, v.y); o.y = pack2(v.z, v.w);
    *(uint2*)(d + i) = o;
  } else {
    for (; i < n; ++i) d[i] = f2bf(s[i]);
  }
}

// ---------------- 256x256 8-phase NT GEMM (unchanged from R3) ----------------
template <typename OutT>
__global__ __launch_bounds__(512, 2)
void k_gemm256(const u16* __restrict__ A, const u16* __restrict__ Bw,
               OutT* __restrict__ C, int Nld, int Ncap, int K) {
  __shared__ u16 SA[2][2][128 * 64];
  __shared__ u16 SB[2][2][128 * 64];
  const int t = threadIdx.x;
  const int lane = t & 63, wave = t >> 6;
  const int wr = wave >> 2, wc = wave & 3;
  const int lq = lane & 15, lg = lane >> 4;
  const int m0 = blockIdx.y * 256, n0 = blockIdx.x * 256;
  const int NT = K >> 6;

  const int r0 = t >> 3;
  const int cs = ((t & 7) ^ (r0 & 7)) * 8;

  auto stageA = [&](int d, int h, int kt) {
    const u16* g = A + (size_t)(m0 + h * 128) * K + kt * 64;
    u16* l = &SA[d][h][0];
    gload_lds16(g + (size_t)r0 * K + cs, l + t * 8);
    gload_lds16(g + (size_t)(r0 + 64) * K + cs, l + (t + 512) * 8);
  };
  auto stageB = [&](int d, int h, int kt) {
    const u16* g = Bw + (size_t)(n0 + h * 128) * K + kt * 64;
    u16* l = &SB[d][h][0];
    gload_lds16(g + (size_t)r0 * K + cs, l + t * 8);
    gload_lds16(g + (size_t)(r0 + 64) * K + cs, l + (t + 512) * 8);
  };
  auto rdA = [&](int d, int m, int k) -> bf16x8 {
    int row = m * 16 + lq;
    return *(const bf16x8*)(&SA[d][wr][0] + row * 64 + (((k * 4 + lg) ^ (row & 7)) * 8));
  };
  auto rdB = [&](int d, int n, int k) -> bf16x8 {
    int row = (wc & 1) * 64 + n * 16 + lq;
    return *(const bf16x8*)(&SB[d][wc >> 1][0] + row * 64 + (((k * 4 + lg) ^ (row & 7)) * 8));
  };

  f32x4 acc[8][4] = {};
  bf16x8 a[8][2], b[4][2];

  stageA(0, 0, 0); stageA(0, 1, 0); stageB(0, 0, 0); stageB(0, 1, 0);
  if (NT > 1) { stageA(1, 0, 1); stageA(1, 1, 1); stageB(1, 0, 1); }
  asm volatile("s_waitcnt vmcnt(6)" ::: "memory");
  __builtin_amdgcn_s_barrier();

  for (int T = 0; T < NT; ++T) {
    const int d = T & 1;
#pragma unroll
    for (int m = 0; m < 4; ++m) { a[m][0] = rdA(d, m, 0); a[m][1] = rdA(d, m, 1); }
#pragma unroll
    for (int n = 0; n < 2; ++n) { b[n][0] = rdB(d, n, 0); b[n][1] = rdB(d, n, 1); }
    if (T + 1 < NT) stageB(d ^ 1, 1, T + 1);
    asm volatile("s_waitcnt lgkmcnt(8)" ::: "memory");
    __builtin_amdgcn_s_barrier();
    asm volatile("s_waitcnt lgkmcnt(0)" ::: "memory");
    __builtin_amdgcn_s_setprio(1);
#pragma unroll
    for (int m = 0; m < 4; ++m)
#pragma unroll
      for (int n = 0; n < 2; ++n) {
        acc[m][n] = __builtin_amdgcn_mfma_f32_16x16x32_bf16(a[m][0], b[n][0], acc[m][n], 0, 0, 0);
        acc[m][n] = __builtin_amdgcn_mfma_f32_16x16x32_bf16(a[m][1], b[n][1], acc[m][n], 0, 0, 0);
      }
    __builtin_amdgcn_s_setprio(0);
    __builtin_amdgcn_s_barrier();
#pragma unroll
    for (int m = 4; m < 8; ++m) { a[m][0] = rdA(d, m, 0); a[m][1] = rdA(d, m, 1); }
#pragma unroll
    for (int n = 2; n < 4; ++n) { b[n][0] = rdB(d, n, 0); b[n][1] = rdB(d, n, 1); }
    asm volatile("s_waitcnt lgkmcnt(8)" ::: "memory");
    __builtin_amdgcn_s_barrier();
    asm volatile("s_waitcnt lgkmcnt(0)" ::: "memory");
    __builtin_amdgcn_s_setprio(1);
#pragma unroll
    for (int m = 4; m < 8; ++m)
#pragma unroll
      for (int n = 0; n < 2; ++n) {
        acc[m][n] = __builtin_amdgcn_mfma_f32_16x16x32_bf16(a[m][0], b[n][0], acc[m][n], 0, 0, 0);
        acc[m][n] = __builtin_amdgcn_mfma_f32_16x16x32_bf16(a[m][1], b[n][1], acc[m][n], 0, 0, 0);
      }
    __builtin_amdgcn_s_setprio(0);
    __builtin_amdgcn_s_barrier();
    if (T + 2 < NT) { stageA(d, 0, T + 2); stageA(d, 1, T + 2); }
    __builtin_amdgcn_s_barrier();
    __builtin_amdgcn_s_setprio(1);
#pragma unroll
    for (int m = 0; m < 4; ++m)
#pragma unroll
      for (int n = 2; n < 4; ++n) {
        acc[m][n] = __builtin_amdgcn_mfma_f32_16x16x32_bf16(a[m][0], b[n][0], acc[m][n], 0, 0, 0);
        acc[m][n] = __builtin_amdgcn_mfma_f32_16x16x32_bf16(a[m][1], b[n][1], acc[m][n], 0, 0, 0);
      }
    __builtin_amdgcn_s_setprio(0);
    __builtin_amdgcn_s_barrier();
    if (T + 2 < NT) stageB(d, 0, T + 2);
    __builtin_amdgcn_s_barrier();
    __builtin_amdgcn_s_setprio(1);
#pragma unroll
    for (int m = 4; m < 8; ++m)
#pragma unroll
      for (int n = 2; n < 4; ++n) {
        acc[m][n] = __builtin_amdgcn_mfma_f32_16x16x32_bf16(a[m][0], b[n][0], acc[m][n], 0, 0, 0);
        acc[m][n] = __builtin_amdgcn_mfma_f32_16x16x32_bf16(a[m][1], b[n][1], acc[m][n], 0, 0, 0);
      }
    __builtin_amdgcn_s_setprio(0);
    if (T + 2 < NT)      asm volatile("s_waitcnt vmcnt(6)" ::: "memory");
    else if (T + 1 < NT) asm volatile("s_waitcnt vmcnt(0)" ::: "memory");
    __builtin_amdgcn_s_barrier();
  }

#pragma unroll
  for (int m = 0; m < 8; ++m)
#pragma unroll
    for (int n = 0; n < 4; ++n) {
      const int col = n0 + wc * 64 + n * 16 + lq;
      if (col < Ncap) {
        const int row = m0 + wr * 128 + m * 16 + lg * 4;
#pragma unroll
        for (int r = 0; r < 4; ++r) {
          float v = acc[m][n][r];
          if constexpr (std::is_same<OutT, float>::value)
            C[(size_t)(row + r) * Nld + col] = v;
          else
            C[(size_t)(row + r) * Nld + col] = f2bf(v);
        }
      }
    }
}

// ---------------- RMSNorm ----------------
__global__ __launch_bounds__(256)
void k_rmsnorm(const u16* __restrict__ x, const float* __restrict__ w,
               u16* __restrict__ y, int D, int xstride) {
  const int row = blockIdx.x;
  const u16* xr = x + (size_t)row * xstride;
  float ss = 0.f;
  for (int i = threadIdx.x; i < D; i += 256) { float v = bf2f(xr[i]); ss += v * v; }
#pragma unroll
  for (int o = 1; o < 64; o <<= 1) ss += __shfl_xor(ss, o);
  __shared__ float red[4];
  if ((threadIdx.x & 63) == 0) red[threadIdx.x >> 6] = ss;
  __syncthreads();
  float rs = rsqrtf((red[0] + red[1] + red[2] + red[3]) / (float)D + 1e-6f);
  u16* yr = y + (size_t)row * D;
  for (int i = threadIdx.x; i < D; i += 256) yr[i] = f2bf(bf2f(xr[i]) * rs * w[i]);
}

// ---------------- pack Q ----------------
__global__ void k_pack_q(const u16* __restrict__ qf, const int* __restrict__ pos,
                         u16* __restrict__ Qp) {
  int idx = blockIdx.x * 256 + threadIdx.x;
  int d = idx % QHD;
  int r0 = idx / QHD;
  int s = r0 % SS;
  int bh = r0 / SS;
  int b = bh >> 4, h = bh & 15;
  int token = b * SS + s;
  const u16* src = qf + (size_t)token * (NH * QHD) + h * QHD;
  u16 outv;
  if (d < NOPE) {
    outv = src[d];
  } else {
    int rr = d - NOPE;
    int j = rr & 31;
    float x0 = bf2f(src[NOPE + 2 * j]), x1 = bf2f(src[NOPE + 2 * j + 1]);
    float ang = (float)pos[b * SS + s] * __expf(-(float)j * LN1E4_32);
    float sn, c; sincosf(ang, &sn, &c);
    outv = f2bf(rr < 32 ? (x0 * c - x1 * sn) : (x1 * c + x0 * sn));
  }
  Qp[idx] = outv;
}

// ---------------- pack K ----------------
__global__ void k_pack_k(const u16* __restrict__ kvf, const u16* __restrict__ ac,
                         const int* __restrict__ pos, u16* __restrict__ Kp) {
  int idx = blockIdx.x * 256 + threadIdx.x;
  int d = idx % QHD;
  int r0 = idx / QHD;
  int s = r0 % SS;
  int bh = r0 / SS;
  int b = bh >> 4, h = bh & 15;
  int token = b * SS + s;
  u16 outv;
  if (d < NOPE) {
    outv = kvf[(size_t)token * (NH * 256) + h * 256 + d];
  } else {
    const u16* pe = ac + (size_t)token * NCOMB + (QL + KVL);
    int rr = d - NOPE;
    int j = rr & 31;
    float x0 = bf2f(pe[2 * j]), x1 = bf2f(pe[2 * j + 1]);
    float ang = (float)pos[b * SS + s] * __expf(-(float)j * LN1E4_32);
    float sn, c; sincosf(ang, &sn, &c);
    outv = f2bf(rr < 32 ? (x0 * c - x1 * sn) : (x1 * c + x0 * sn));
  }
  Kp[idx] = outv;
}

// ---------------- pack V^T via LDS-tiled transpose ----------------
// kvfull[token][h*256+128+v] -> VT[bh][v][s]. Tile 64s x 64v, both global sides
// coalesced (uint4), LDS XOR-swizzled (col ^= 8*(row&7)), <=2-way banks.
// grid (SS/64, VD/64, BB*NH), 256 thr.
__global__ __launch_bounds__(256)
void k_pack_v(const u16* __restrict__ kvf, u16* __restrict__ VT) {
  __shared__ u16 L[64 * 64];
  const int s0 = blockIdx.x * 64, v0 = blockIdx.y * 64;
  const int bh = blockIdx.z, b = bh >> 4, h = bh & 15;
  const int t = threadIdx.x;
  const int sr = t >> 3, vc = (t & 7) * 8;
#pragma unroll
  for (int i = 0; i < 2; ++i) {
    const int r = sr + i * 32;
    const u16* src = kvf + (size_t)(b * SS + s0 + r) * (NH * 256) + h * 256 + NOPE + v0 + vc;
    *(uint4*)(&L[r * 64 + (vc ^ (8 * (r & 7)))]) = *(const uint4*)src;
  }
  __syncthreads();
  const int w = t >> 6, l = t & 63;
  u16 tmp[16];
#pragma unroll
  for (int j = 0; j < 16; ++j) {
    const int r = w * 16 + j;
    tmp[j] = L[r * 64 + (l ^ (8 * (r & 7)))];
  }
  u16* dst = VT + (size_t)(bh * 128 + v0 + l) * SS + s0 + w * 16;
  *(uint4*)dst       = ((uint4*)tmp)[0];
  *(uint4*)(dst + 8) = ((uint4*)tmp)[1];
}

// ---------------- causal flash attention ----------------
// Heavy-first dispatch (xb reversal) fixes causal load imbalance; fully-masked
// tiles skip compute (barriers kept); log2-domain softmax (v_exp direct);
// defer-max T13 (skip O-rescale when max grows < 11 log2); setprio on MFMA.
__global__ __launch_bounds__(512)
void k_attn(const u16* __restrict__ Qp, const u16* __restrict__ Kp,
            const u16* __restrict__ VT, u16* __restrict__ Oa) {
  const int bh = blockIdx.y;
  const int xb = gridDim.x - 1 - blockIdx.x;   // heavy blocks dispatch first
  const int t = threadIdx.x, lane = t & 63, wave = t >> 6;
  const int lq = lane & 15, lg = lane >> 4;
  const int q0 = xb * 128 + wave * 16;
  const size_t qkb = (size_t)bh * SS * QHD;
  const size_t vb  = (size_t)bh * VD * SS;

  __shared__ u16 Ks[2][32 * 192];
  __shared__ u16 Vs[2][128 * 32];
  __shared__ u16 Pl[8][512];
  char* pl = (char*)&Pl[wave][0];
  const int swq = ((lq ^ (lq >> 2)) & 3) << 4;

  bf16x8 qf[6];
#pragma unroll
  for (int ch = 0; ch < 6; ++ch)
    qf[ch] = *(const bf16x8*)(Qp + qkb + (size_t)(q0 + lq) * QHD + ch * 32 + lg * 8);

  float m = -1e30f, lsum = 0.f;
  f32x4 o[8];
#pragma unroll
  for (int vc = 0; vc < 8; ++vc) o[vc] = (f32x4){0.f, 0.f, 0.f, 0.f};

  const int nt = (xb + 1) * 4;

  auto stage = [&](int buf, int kb) {
    {
      int c = t;
      int row = c / 24, sl = c % 24;
      gload_lds16(Kp + qkb + (size_t)(kb + row) * QHD + (sl ^ (row & 7)) * 8,
                  &Ks[buf][0] + c * 8);
    }
    if (t < 256) {
      int c = 512 + t;
      int row = c / 24, sl = c % 24;
      gload_lds16(Kp + qkb + (size_t)(kb + row) * QHD + (sl ^ (row & 7)) * 8,
                  &Ks[buf][0] + c * 8);
    }
    {
      int row = t >> 2, sl = t & 3;
      gload_lds16(VT + vb + (size_t)row * SS + kb + (sl ^ ((row >> 1) & 3)) * 8,
                  &Vs[buf][0] + t * 8);
    }
  };

  stage(0, 0);
  asm volatile("s_waitcnt vmcnt(0)" ::: "memory");
  __builtin_amdgcn_s_barrier();

  for (int tt = 0; tt < nt; ++tt) {
    const int cur = tt & 1;
    if (tt + 1 < nt) stage(cur ^ 1, (tt + 1) * 32);
    const int kb = tt * 32;

    if (kb < q0 + 16) {          // wave-uniform: skip fully-masked tiles
      f32x4 slo = (f32x4){0.f, 0.f, 0.f, 0.f};
      f32x4 shi = (f32x4){0.f, 0.f, 0.f, 0.f};
      __builtin_amdgcn_s_setprio(1);
#pragma unroll
      for (int ch = 0; ch < 6; ++ch) {
        const int ps = (ch * 4 + lg) ^ (lq & 7);
        bf16x8 klo = *(const bf16x8*)(&Ks[cur][0] + (lq * 24 + ps) * 8);
        bf16x8 khi = *(const bf16x8*)(&Ks[cur][0] + ((16 + lq) * 24 + ps) * 8);
        slo = __builtin_amdgcn_mfma_f32_16x16x32_bf16(klo, qf[ch], slo, 0, 0, 0);
        shi = __builtin_amdgcn_mfma_f32_16x16x32_bf16(khi, qf[ch], shi, 0, 0, 0);
      }
      __builtin_amdgcn_s_setprio(0);

      const int qrow = q0 + lq;
      float mx = -1e30f;
#pragma unroll
      for (int r = 0; r < 4; ++r) {
        int klo = kb + lg * 4 + r;
        float v0 = (klo <= qrow)        ? slo[r] * SCALE2 : -1e30f;
        float v1 = ((klo + 16) <= qrow) ? shi[r] * SCALE2 : -1e30f;
        slo[r] = v0; shi[r] = v1;
        mx = fmaxf(mx, fmaxf(v0, v1));
      }
      mx = fmaxf(mx, __shfl_xor(mx, 16));
      mx = fmaxf(mx, __shfl_xor(mx, 32));
      if (!__all(mx - m <= 11.0f)) {       // defer-max: rescale only on real growth
        float mnew = fmaxf(m, mx);
        float fac = fexp2(m - mnew);
        lsum *= fac;
#pragma unroll
        for (int vc = 0; vc < 8; ++vc) {
          o[vc][0] *= fac; o[vc][1] *= fac; o[vc][2] *= fac; o[vc][3] *= fac;
        }
        m = mnew;
      }
      float p0 = fexp2(slo[0] - m), p1 = fexp2(slo[1] - m);
      float p2 = fexp2(slo[2] - m), p3 = fexp2(slo[3] - m);
      float p4 = fexp2(shi[0] - m), p5 = fexp2(shi[1] - m);
      float p6 = fexp2(shi[2] - m), p7 = fexp2(shi[3] - m);
      float ps2 = ((p0 + p1) + (p2 + p3)) + ((p4 + p5) + (p6 + p7));
      ps2 += __shfl_xor(ps2, 16);
      ps2 += __shfl_xor(ps2, 32);
      lsum += ps2;

      *(u32*)(pl + lq * 64 + ((8 * lg)          ^ swq)) = pack2(p0, p1);
      *(u32*)(pl + lq * 64 + ((8 * lg + 4)      ^ swq)) = pack2(p2, p3);
      *(u32*)(pl + lq * 64 + ((32 + 8 * lg)     ^ swq)) = pack2(p4, p5);
      *(u32*)(pl + lq * 64 + ((32 + 8 * lg + 4) ^ swq)) = pack2(p6, p7);
      bf16x8 pf = *(const bf16x8*)(pl + lq * 64 + ((16 * lg) ^ swq));
      __builtin_amdgcn_s_setprio(1);
#pragma unroll
      for (int vc = 0; vc < 8; ++vc) {
        const int rv = vc * 16 + lq;
        const int psv = lg ^ ((rv >> 1) & 3);
        bf16x8 vf = *(const bf16x8*)(&Vs[cur][0] + rv * 32 + psv * 8);
        o[vc] = __builtin_amdgcn_mfma_f32_16x16x32_bf16(vf, pf, o[vc], 0, 0, 0);
      }
      __builtin_amdgcn_s_setprio(0);
    }

    asm volatile("s_waitcnt vmcnt(0)" ::: "memory");
    __builtin_amdgcn_s_barrier();
  }

  const float inv = 1.0f / lsum;
  const int b = bh >> 4, h = bh & 15;
  u16* orow = Oa + (size_t)(b * SS + q0 + lq) * (NH * VD) + h * VD;
#pragma unroll
  for (int vc = 0; vc < 8; ++vc)
#pragma unroll
    for (int r = 0; r < 4; ++r)
      orow[vc * 16 + lg * 4 + r] = f2bf(o[vc][r] * inv);
}

// ---------------- host launch ----------------
extern "C" void kernel_launch(void* const* d_in, const int* in_sizes, int n_in,
                              void* d_out, int out_size, void* d_ws, size_t ws_size,
                              hipStream_t stream) {
  (void)in_sizes; (void)n_in; (void)out_size; (void)ws_size;
  const float* hidden  = (const float*)d_in[0];
  const int*   pos     = (const int*)d_in[2];
  const float* q_a_w   = (const float*)d_in[3];
  const float* q_a_ln  = (const float*)d_in[4];
  const float* q_b_w   = (const float*)d_in[5];
  const float* kv_a_w  = (const float*)d_in[6];
  const float* kv_a_ln = (const float*)d_in[7];
  const float* kv_b_w  = (const float*)d_in[8];
  const float* o_w     = (const float*)d_in[9];

  char* ws = (char*)d_ws;
  u16* hid_bf = (u16*)(ws + 0);          // 16,777,216 (reused as VT after GEMM1)
  u16* VT     = (u16*)(ws + 0);
  u16* w_comb = (u16*)(ws + 16777216);
  u16* w_qb   = (u16*)(ws + 25690112);
  u16* w_kvb  = (u16*)(ws + 35127296);
  u16* w_o    = (u16*)(ws + 39321600);
  u16* ac     = (u16*)(ws + 47710208);
  u16* qa_n   = (u16*)(ws + 65536000);
  u16* Qpk    = (u16*)(ws + 47710208);
  u16* kv_n   = (u16*)(ws + 78118912);
  u16* qfull  = (u16*)(ws + 82313216);
  u16* attn_o = (u16*)(ws + 82313216);
  u16* kvfull = (u16*)(ws + 107479040);
  u16* Kpk    = (u16*)(ws + 141033472);

  k_f2bf<<<(TOK * HID) / 1024, 256, 0, stream>>>(hidden, hid_bf, TOK * HID);
  k_f2bf<<<(QL * HID) / 1024, 256, 0, stream>>>(q_a_w, w_comb, QL * HID);
  k_f2bf<<<((KVL + 64) * HID) / 1024, 256, 0, stream>>>(kv_a_w, w_comb + QL * HID, (KVL + 64) * HID);
  k_f2bf<<<(NH * QHD * QL) / 1024, 256, 0, stream>>>(q_b_w, w_qb, NH * QHD * QL);
  k_f2bf<<<(NH * 256 * KVL) / 1024, 256, 0, stream>>>(kv_b_w, w_kvb, NH * 256 * KVL);
  k_f2bf<<<(HID * NH * VD) / 1024, 256, 0, stream>>>(o_w, w_o, HID * NH * VD);

  k_gemm256<u16><<<dim3(9, TOK / 256), 512, 0, stream>>>(hid_bf, w_comb, ac, NCOMB, NREAL, HID);
  k_rmsnorm<<<TOK, 256, 0, stream>>>(ac,      q_a_ln,  qa_n, QL,  NCOMB);
  k_rmsnorm<<<TOK, 256, 0, stream>>>(ac + QL, kv_a_ln, kv_n, KVL, NCOMB);
  k_gemm256<u16><<<dim3(12, TOK / 256), 512, 0, stream>>>(qa_n, w_qb, qfull, NH * QHD, NH * QHD, QL);
  k_gemm256<u16><<<dim3(16, TOK / 256), 512, 0, stream>>>(kv_n, w_kvb, kvfull, NH * 256, NH * 256, KVL);
  k_pack_k<<<(BB * NH * SS * QHD) / 256, 256, 0, stream>>>(kvfull, ac, pos, Kpk);
  k_pack_v<<<dim3(SS / 64, VD / 64, BB * NH), 256, 0, stream>>>(kvfull, VT);
  k_pack_q<<<(BB * NH * SS * QHD) / 256, 256, 0, stream>>>(qfull, pos, Qpk);
  k_attn<<<dim3(SS / 128, BB * NH), 512, 0, stream>>>(Qpk, Kpk, VT, attn_o);
  k_gemm256<float><<<dim3(8, TOK / 256), 512, 0, stream>>>(attn_o, w_o, (float*)d_out, HID, HID, NH * VD);
}

// Round 5
// 370.600 us; speedup vs baseline: 2.3958x; 1.1400x over previous
//
#include <hip/hip_runtime.h>
#include <hip/hip_bf16.h>
#include <stdint.h>
#include <type_traits>

#define DEVINL __device__ __forceinline__

typedef unsigned short u16;
typedef unsigned int   u32;
typedef short bf16x8 __attribute__((ext_vector_type(8)));
typedef float f32x4  __attribute__((ext_vector_type(4)));

// ---- problem constants ----
constexpr int BB   = 2,  SS  = 2048, HID = 2048, NH = 16;
constexpr int NOPE = 128, VD = 128, QHD = 192;
constexpr int QL   = 1536, KVL = 512;
constexpr int TOK  = BB * SS;            // 4096 tokens
constexpr int NCOMB = 2176;              // ac row stride
constexpr int NREAL = 2112;              // real combined output cols (1536+512+64)
constexpr float SCALE2    = 0.10412907368573824f;   // 192^-0.5 * log2(e)
constexpr float LN1E4_32  = 0.28782313662425575f;   // ln(10000)/32

DEVINL float bf2f(u16 u) { union { u32 u; float f; } v; v.u = (u32)u << 16; return v.f; }
DEVINL u16 f2bf(float f) {
  union { float f; u32 u; } v; v.f = f;
  u32 r = v.u + 0x7fffu + ((v.u >> 16) & 1u);
  return (u16)(r >> 16);
}
DEVINL u32 pack2(float a, float b) { return (u32)f2bf(a) | ((u32)f2bf(b) << 16); }

DEVINL float fexp2(float x) {
#if __has_builtin(__builtin_amdgcn_exp2f)
  return __builtin_amdgcn_exp2f(x);
#else
  return __expf(x * 0.6931471805599453f);
#endif
}

DEVINL void gload_lds16(const u16* g, u16* l) {
  __builtin_amdgcn_global_load_lds(
      (const __attribute__((address_space(1))) void*)g,
      (__attribute__((address_space(3))) void*)l, 16, 0, 0);
}

// ---------------- fp32 -> bf16 conversion ----------------
__global__ void k_f2bf(const float* __restrict__ s, u16* __restrict__ d, int n) {
  int i = (blockIdx.x * 256 + threadIdx.x) * 4;
  if (i + 4 <= n) {
    float4 v = *(const float4*)(s + i);
    uint2 o; o.x = pack2(v.x, v.y); o.y = pack2(v.z, v.w);
    *(uint2*)(d + i) = o;
  } else {
    for (; i < n; ++i) d[i] = f2bf(s[i]);
  }
}

// ---------------- 256x256 8-phase NT GEMM (unchanged) ----------------
template <typename OutT>
__global__ __launch_bounds__(512, 2)
void k_gemm256(const u16* __restrict__ A, const u16* __restrict__ Bw,
               OutT* __restrict__ C, int Nld, int Ncap, int K) {
  __shared__ u16 SA[2][2][128 * 64];
  __shared__ u16 SB[2][2][128 * 64];
  const int t = threadIdx.x;
  const int lane = t & 63, wave = t >> 6;
  const int wr = wave >> 2, wc = wave & 3;
  const int lq = lane & 15, lg = lane >> 4;
  const int m0 = blockIdx.y * 256, n0 = blockIdx.x * 256;
  const int NT = K >> 6;

  const int r0 = t >> 3;
  const int cs = ((t & 7) ^ (r0 & 7)) * 8;

  auto stageA = [&](int d, int h, int kt) {
    const u16* g = A + (size_t)(m0 + h * 128) * K + kt * 64;
    u16* l = &SA[d][h][0];
    gload_lds16(g + (size_t)r0 * K + cs, l + t * 8);
    gload_lds16(g + (size_t)(r0 + 64) * K + cs, l + (t + 512) * 8);
  };
  auto stageB = [&](int d, int h, int kt) {
    const u16* g = Bw + (size_t)(n0 + h * 128) * K + kt * 64;
    u16* l = &SB[d][h][0];
    gload_lds16(g + (size_t)r0 * K + cs, l + t * 8);
    gload_lds16(g + (size_t)(r0 + 64) * K + cs, l + (t + 512) * 8);
  };
  auto rdA = [&](int d, int m, int k) -> bf16x8 {
    int row = m * 16 + lq;
    return *(const bf16x8*)(&SA[d][wr][0] + row * 64 + (((k * 4 + lg) ^ (row & 7)) * 8));
  };
  auto rdB = [&](int d, int n, int k) -> bf16x8 {
    int row = (wc & 1) * 64 + n * 16 + lq;
    return *(const bf16x8*)(&SB[d][wc >> 1][0] + row * 64 + (((k * 4 + lg) ^ (row & 7)) * 8));
  };

  f32x4 acc[8][4] = {};
  bf16x8 a[8][2], b[4][2];

  stageA(0, 0, 0); stageA(0, 1, 0); stageB(0, 0, 0); stageB(0, 1, 0);
  if (NT > 1) { stageA(1, 0, 1); stageA(1, 1, 1); stageB(1, 0, 1); }
  asm volatile("s_waitcnt vmcnt(6)" ::: "memory");
  __builtin_amdgcn_s_barrier();

  for (int T = 0; T < NT; ++T) {
    const int d = T & 1;
#pragma unroll
    for (int m = 0; m < 4; ++m) { a[m][0] = rdA(d, m, 0); a[m][1] = rdA(d, m, 1); }
#pragma unroll
    for (int n = 0; n < 2; ++n) { b[n][0] = rdB(d, n, 0); b[n][1] = rdB(d, n, 1); }
    if (T + 1 < NT) stageB(d ^ 1, 1, T + 1);
    asm volatile("s_waitcnt lgkmcnt(8)" ::: "memory");
    __builtin_amdgcn_s_barrier();
    asm volatile("s_waitcnt lgkmcnt(0)" ::: "memory");
    __builtin_amdgcn_s_setprio(1);
#pragma unroll
    for (int m = 0; m < 4; ++m)
#pragma unroll
      for (int n = 0; n < 2; ++n) {
        acc[m][n] = __builtin_amdgcn_mfma_f32_16x16x32_bf16(a[m][0], b[n][0], acc[m][n], 0, 0, 0);
        acc[m][n] = __builtin_amdgcn_mfma_f32_16x16x32_bf16(a[m][1], b[n][1], acc[m][n], 0, 0, 0);
      }
    __builtin_amdgcn_s_setprio(0);
    __builtin_amdgcn_s_barrier();
#pragma unroll
    for (int m = 4; m < 8; ++m) { a[m][0] = rdA(d, m, 0); a[m][1] = rdA(d, m, 1); }
#pragma unroll
    for (int n = 2; n < 4; ++n) { b[n][0] = rdB(d, n, 0); b[n][1] = rdB(d, n, 1); }
    asm volatile("s_waitcnt lgkmcnt(8)" ::: "memory");
    __builtin_amdgcn_s_barrier();
    asm volatile("s_waitcnt lgkmcnt(0)" ::: "memory");
    __builtin_amdgcn_s_setprio(1);
#pragma unroll
    for (int m = 4; m < 8; ++m)
#pragma unroll
      for (int n = 0; n < 2; ++n) {
        acc[m][n] = __builtin_amdgcn_mfma_f32_16x16x32_bf16(a[m][0], b[n][0], acc[m][n], 0, 0, 0);
        acc[m][n] = __builtin_amdgcn_mfma_f32_16x16x32_bf16(a[m][1], b[n][1], acc[m][n], 0, 0, 0);
      }
    __builtin_amdgcn_s_setprio(0);
    __builtin_amdgcn_s_barrier();
    if (T + 2 < NT) { stageA(d, 0, T + 2); stageA(d, 1, T + 2); }
    __builtin_amdgcn_s_barrier();
    __builtin_amdgcn_s_setprio(1);
#pragma unroll
    for (int m = 0; m < 4; ++m)
#pragma unroll
      for (int n = 2; n < 4; ++n) {
        acc[m][n] = __builtin_amdgcn_mfma_f32_16x16x32_bf16(a[m][0], b[n][0], acc[m][n], 0, 0, 0);
        acc[m][n] = __builtin_amdgcn_mfma_f32_16x16x32_bf16(a[m][1], b[n][1], acc[m][n], 0, 0, 0);
      }
    __builtin_amdgcn_s_setprio(0);
    __builtin_amdgcn_s_barrier();
    if (T + 2 < NT) stageB(d, 0, T + 2);
    __builtin_amdgcn_s_barrier();
    __builtin_amdgcn_s_setprio(1);
#pragma unroll
    for (int m = 4; m < 8; ++m)
#pragma unroll
      for (int n = 2; n < 4; ++n) {
        acc[m][n] = __builtin_amdgcn_mfma_f32_16x16x32_bf16(a[m][0], b[n][0], acc[m][n], 0, 0, 0);
        acc[m][n] = __builtin_amdgcn_mfma_f32_16x16x32_bf16(a[m][1], b[n][1], acc[m][n], 0, 0, 0);
      }
    __builtin_amdgcn_s_setprio(0);
    if (T + 2 < NT)      asm volatile("s_waitcnt vmcnt(6)" ::: "memory");
    else if (T + 1 < NT) asm volatile("s_waitcnt vmcnt(0)" ::: "memory");
    __builtin_amdgcn_s_barrier();
  }

#pragma unroll
  for (int m = 0; m < 8; ++m)
#pragma unroll
    for (int n = 0; n < 4; ++n) {
      const int col = n0 + wc * 64 + n * 16 + lq;
      if (col < Ncap) {
        const int row = m0 + wr * 128 + m * 16 + lg * 4;
#pragma unroll
        for (int r = 0; r < 4; ++r) {
          float v = acc[m][n][r];
          if constexpr (std::is_same<OutT, float>::value)
            C[(size_t)(row + r) * Nld + col] = v;
          else
            C[(size_t)(row + r) * Nld + col] = f2bf(v);
        }
      }
    }
}

// ---------------- RMSNorm ----------------
__global__ __launch_bounds__(256)
void k_rmsnorm(const u16* __restrict__ x, const float* __restrict__ w,
               u16* __restrict__ y, int D, int xstride) {
  const int row = blockIdx.x;
  const u16* xr = x + (size_t)row * xstride;
  float ss = 0.f;
  for (int i = threadIdx.x; i < D; i += 256) { float v = bf2f(xr[i]); ss += v * v; }
#pragma unroll
  for (int o = 1; o < 64; o <<= 1) ss += __shfl_xor(ss, o);
  __shared__ float red[4];
  if ((threadIdx.x & 63) == 0) red[threadIdx.x >> 6] = ss;
  __syncthreads();
  float rs = rsqrtf((red[0] + red[1] + red[2] + red[3]) / (float)D + 1e-6f);
  u16* yr = y + (size_t)row * D;
  for (int i = threadIdx.x; i < D; i += 256) yr[i] = f2bf(bf2f(xr[i]) * rs * w[i]);
}

// ---------------- rope k_pe: ac[:, 2048:2112] -> peR (B*S, 64), in-place pair rotation ----------------
__global__ __launch_bounds__(256)
void k_rope_pe(const u16* __restrict__ ac, const int* __restrict__ pos,
               u16* __restrict__ peR) {
  int idx = blockIdx.x * 256 + threadIdx.x;      // TOK*32 pairs
  int token = idx >> 5, j = idx & 31;
  const u16* src = ac + (size_t)token * NCOMB + (QL + KVL) + 2 * j;
  float x0 = bf2f(src[0]), x1 = bf2f(src[1]);
  float ang = (float)pos[token] * __expf(-(float)j * LN1E4_32);
  float sn, cs; sincosf(ang, &sn, &cs);
  *(u32*)(peR + (size_t)token * 64 + 2 * j) = pack2(x0 * cs - x1 * sn, x1 * cs + x0 * sn);
}

// ---------------- pack V^T via LDS-tiled transpose (unchanged) ----------------
__global__ __launch_bounds__(256)
void k_pack_v(const u16* __restrict__ kvf, u16* __restrict__ VT) {
  __shared__ u16 L[64 * 64];
  const int s0 = blockIdx.x * 64, v0 = blockIdx.y * 64;
  const int bh = blockIdx.z, b = bh >> 4, h = bh & 15;
  const int t = threadIdx.x;
  const int sr = t >> 3, vc = (t & 7) * 8;
#pragma unroll
  for (int i = 0; i < 2; ++i) {
    const int r = sr + i * 32;
    const u16* src = kvf + (size_t)(b * SS + s0 + r) * (NH * 256) + h * 256 + NOPE + v0 + vc;
    *(uint4*)(&L[r * 64 + (vc ^ (8 * (r & 7)))]) = *(const uint4*)src;
  }
  __syncthreads();
  const int w = t >> 6, l = t & 63;
  u16 tmp[16];
#pragma unroll
  for (int j = 0; j < 16; ++j) {
    const int r = w * 16 + j;
    tmp[j] = L[r * 64 + (l ^ (8 * (r & 7)))];
  }
  u16* dst = VT + (size_t)(bh * 128 + v0 + l) * SS + s0 + w * 16;
  *(uint4*)dst       = ((uint4*)tmp)[0];
  *(uint4*)(dst + 8) = ((uint4*)tmp)[1];
}

// ---------------- causal flash attention, paired-block balanced, fused Q/K reads ----------------
// grid (8, B*H). Block x processes q-tiles x and 15-x sequentially -> uniform 17
// key-128-tiles per block (zero drain). Q read from qfull with in-reg RoPE on q_pe
// (in-place pair rotation, matching k_rope_pe); K staged from kvfull (nope) + peR (pe)
// -- XOR swizzle slot^(row&7) keeps slots 0..15 / 16..23 region-closed.
__global__ __launch_bounds__(512)
void k_attn(const u16* __restrict__ Qf, const u16* __restrict__ kvf,
            const u16* __restrict__ peR, const u16* __restrict__ VT,
            const int* __restrict__ pos, u16* __restrict__ Oa) {
  const int bh = blockIdx.y, b = bh >> 4, h = bh & 15;
  const int t = threadIdx.x, lane = t & 63, wave = t >> 6;
  const int lq = lane & 15, lg = lane >> 4;
  const size_t vb = (size_t)bh * VD * SS;

  __shared__ u16 Ks[2][32 * 192];
  __shared__ u16 Vs[2][128 * 32];
  __shared__ u16 Pl[8][512];
  char* pl = (char*)&Pl[wave][0];
  const int swq = ((lq ^ (lq >> 2)) & 3) << 4;

  auto stage = [&](int buf, int kb) {
    {
      int c = t, row = c / 24, sl = c % 24;
      int sg = sl ^ (row & 7);
      const u16* src = (sg < 16)
          ? kvf + (size_t)(b * SS + kb + row) * (NH * 256) + h * 256 + sg * 8
          : peR + (size_t)(b * SS + kb + row) * 64 + (sg - 16) * 8;
      gload_lds16(src, &Ks[buf][0] + c * 8);
    }
    if (t < 256) {
      int c = 512 + t, row = c / 24, sl = c % 24;
      int sg = sl ^ (row & 7);
      const u16* src = (sg < 16)
          ? kvf + (size_t)(b * SS + kb + row) * (NH * 256) + h * 256 + sg * 8
          : peR + (size_t)(b * SS + kb + row) * 64 + (sg - 16) * 8;
      gload_lds16(src, &Ks[buf][0] + c * 8);
    }
    {
      int row = t >> 2, sl = t & 3;
      gload_lds16(VT + vb + (size_t)row * SS + kb + (sl ^ ((row >> 1) & 3)) * 8,
                  &Vs[buf][0] + t * 8);
    }
  };

  for (int pass = 0; pass < 2; ++pass) {
    const int xb = pass ? (15 - (int)blockIdx.x) : (int)blockIdx.x;
    const int q0 = xb * 128 + wave * 16;
    const int token = b * SS + q0 + lq;

    bf16x8 qf[6];
#pragma unroll
    for (int ch = 0; ch < 6; ++ch)
      qf[ch] = *(const bf16x8*)(Qf + (size_t)token * (NH * QHD) + h * QHD + ch * 32 + lg * 8);
    // in-reg RoPE on q_pe chunks (4,5): pair (2j,2j+1) rotated by pos*invfreq(j)
    const float posv = (float)pos[token];
#pragma unroll
    for (int ch = 4; ch < 6; ++ch)
#pragma unroll
      for (int p = 0; p < 4; ++p) {
        const int j = (ch - 4) * 16 + lg * 4 + p;
        const float ang = posv * __expf(-(float)j * LN1E4_32);
        float sn, cs; sincosf(ang, &sn, &cs);
        const float x0 = bf2f((u16)qf[ch][2 * p]), x1 = bf2f((u16)qf[ch][2 * p + 1]);
        qf[ch][2 * p]     = (short)f2bf(x0 * cs - x1 * sn);
        qf[ch][2 * p + 1] = (short)f2bf(x1 * cs + x0 * sn);
      }

    float m = -1e30f, lsum = 0.f;
    f32x4 o[8];
#pragma unroll
    for (int vc = 0; vc < 8; ++vc) o[vc] = (f32x4){0.f, 0.f, 0.f, 0.f};

    const int nt = (xb + 1) * 4;

    stage(0, 0);
    asm volatile("s_waitcnt vmcnt(0)" ::: "memory");
    __builtin_amdgcn_s_barrier();

    for (int tt = 0; tt < nt; ++tt) {
      const int cur = tt & 1;
      if (tt + 1 < nt) stage(cur ^ 1, (tt + 1) * 32);
      const int kb = tt * 32;

      if (kb < q0 + 16) {            // wave-uniform skip of fully-masked tiles
        f32x4 slo = (f32x4){0.f, 0.f, 0.f, 0.f};
        f32x4 shi = (f32x4){0.f, 0.f, 0.f, 0.f};
        __builtin_amdgcn_s_setprio(1);
#pragma unroll
        for (int ch = 0; ch < 6; ++ch) {
          const int ps = (ch * 4 + lg) ^ (lq & 7);
          bf16x8 klo = *(const bf16x8*)(&Ks[cur][0] + (lq * 24 + ps) * 8);
          bf16x8 khi = *(const bf16x8*)(&Ks[cur][0] + ((16 + lq) * 24 + ps) * 8);
          slo = __builtin_amdgcn_mfma_f32_16x16x32_bf16(klo, qf[ch], slo, 0, 0, 0);
          shi = __builtin_amdgcn_mfma_f32_16x16x32_bf16(khi, qf[ch], shi, 0, 0, 0);
        }
        __builtin_amdgcn_s_setprio(0);

        const int qrow = q0 + lq;
        float mx = -1e30f;
#pragma unroll
        for (int r = 0; r < 4; ++r) {
          int klo = kb + lg * 4 + r;
          float v0 = (klo <= qrow)        ? slo[r] * SCALE2 : -1e30f;
          float v1 = ((klo + 16) <= qrow) ? shi[r] * SCALE2 : -1e30f;
          slo[r] = v0; shi[r] = v1;
          mx = fmaxf(mx, fmaxf(v0, v1));
        }
        mx = fmaxf(mx, __shfl_xor(mx, 16));
        mx = fmaxf(mx, __shfl_xor(mx, 32));
        if (!__all(mx - m <= 11.0f)) {
          float mnew = fmaxf(m, mx);
          float fac = fexp2(m - mnew);
          lsum *= fac;
#pragma unroll
          for (int vc = 0; vc < 8; ++vc) {
            o[vc][0] *= fac; o[vc][1] *= fac; o[vc][2] *= fac; o[vc][3] *= fac;
          }
          m = mnew;
        }
        float p0 = fexp2(slo[0] - m), p1 = fexp2(slo[1] - m);
        float p2 = fexp2(slo[2] - m), p3 = fexp2(slo[3] - m);
        float p4 = fexp2(shi[0] - m), p5 = fexp2(shi[1] - m);
        float p6 = fexp2(shi[2] - m), p7 = fexp2(shi[3] - m);
        float ps2 = ((p0 + p1) + (p2 + p3)) + ((p4 + p5) + (p6 + p7));
        ps2 += __shfl_xor(ps2, 16);
        ps2 += __shfl_xor(ps2, 32);
        lsum += ps2;

        *(u32*)(pl + lq * 64 + ((8 * lg)          ^ swq)) = pack2(p0, p1);
        *(u32*)(pl + lq * 64 + ((8 * lg + 4)      ^ swq)) = pack2(p2, p3);
        *(u32*)(pl + lq * 64 + ((32 + 8 * lg)     ^ swq)) = pack2(p4, p5);
        *(u32*)(pl + lq * 64 + ((32 + 8 * lg + 4) ^ swq)) = pack2(p6, p7);
        bf16x8 pf = *(const bf16x8*)(pl + lq * 64 + ((16 * lg) ^ swq));
        __builtin_amdgcn_s_setprio(1);
#pragma unroll
        for (int vc = 0; vc < 8; ++vc) {
          const int rv = vc * 16 + lq;
          const int psv = lg ^ ((rv >> 1) & 3);
          bf16x8 vf = *(const bf16x8*)(&Vs[cur][0] + rv * 32 + psv * 8);
          o[vc] = __builtin_amdgcn_mfma_f32_16x16x32_bf16(vf, pf, o[vc], 0, 0, 0);
        }
        __builtin_amdgcn_s_setprio(0);
      }

      asm volatile("s_waitcnt vmcnt(0)" ::: "memory");
      __builtin_amdgcn_s_barrier();
    }

    const float inv = 1.0f / lsum;
    u16* orow = Oa + (size_t)token * (NH * VD) + h * VD;
#pragma unroll
    for (int vc = 0; vc < 8; ++vc) {
      *(u32*)(orow + vc * 16 + lg * 4)     = pack2(o[vc][0] * inv, o[vc][1] * inv);
      *(u32*)(orow + vc * 16 + lg * 4 + 2) = pack2(o[vc][2] * inv, o[vc][3] * inv);
    }
  }
}

// ---------------- host launch ----------------
extern "C" void kernel_launch(void* const* d_in, const int* in_sizes, int n_in,
                              void* d_out, int out_size, void* d_ws, size_t ws_size,
                              hipStream_t stream) {
  (void)in_sizes; (void)n_in; (void)out_size; (void)ws_size;
  const float* hidden  = (const float*)d_in[0];
  const int*   pos     = (const int*)d_in[2];
  const float* q_a_w   = (const float*)d_in[3];
  const float* q_a_ln  = (const float*)d_in[4];
  const float* q_b_w   = (const float*)d_in[5];
  const float* kv_a_w  = (const float*)d_in[6];
  const float* kv_a_ln = (const float*)d_in[7];
  const float* kv_b_w  = (const float*)d_in[8];
  const float* o_w     = (const float*)d_in[9];

  char* ws = (char*)d_ws;
  u16* hid_bf = (u16*)(ws + 0);          // dead after GEMM1; reused as VT
  u16* VT     = (u16*)(ws + 0);
  u16* w_comb = (u16*)(ws + 16777216);
  u16* w_qb   = (u16*)(ws + 25690112);
  u16* w_kvb  = (u16*)(ws + 35127296);
  u16* w_o    = (u16*)(ws + 39321600);
  u16* ac     = (u16*)(ws + 47710208);   // dead after k_rope_pe; reused as attn_o
  u16* attn_o = (u16*)(ws + 47710208);
  u16* qa_n   = (u16*)(ws + 65536000);
  u16* kv_n   = (u16*)(ws + 78118912);
  u16* qfull  = (u16*)(ws + 82313216);
  u16* kvfull = (u16*)(ws + 107479040);
  u16* peR    = (u16*)(ws + 141033472);  // TOK x 64 roped k_pe (524,288 B)

  k_f2bf<<<(TOK * HID) / 1024, 256, 0, stream>>>(hidden, hid_bf, TOK * HID);
  k_f2bf<<<(QL * HID) / 1024, 256, 0, stream>>>(q_a_w, w_comb, QL * HID);
  k_f2bf<<<((KVL + 64) * HID) / 1024, 256, 0, stream>>>(kv_a_w, w_comb + QL * HID, (KVL + 64) * HID);
  k_f2bf<<<(NH * QHD * QL) / 1024, 256, 0, stream>>>(q_b_w, w_qb, NH * QHD * QL);
  k_f2bf<<<(NH * 256 * KVL) / 1024, 256, 0, stream>>>(kv_b_w, w_kvb, NH * 256 * KVL);
  k_f2bf<<<(HID * NH * VD) / 1024, 256, 0, stream>>>(o_w, w_o, HID * NH * VD);

  k_gemm256<u16><<<dim3(9, TOK / 256), 512, 0, stream>>>(hid_bf, w_comb, ac, NCOMB, NREAL, HID);
  k_rmsnorm<<<TOK, 256, 0, stream>>>(ac,      q_a_ln,  qa_n, QL,  NCOMB);
  k_rmsnorm<<<TOK, 256, 0, stream>>>(ac + QL, kv_a_ln, kv_n, KVL, NCOMB);
  k_gemm256<u16><<<dim3(12, TOK / 256), 512, 0, stream>>>(qa_n, w_qb, qfull, NH * QHD, NH * QHD, QL);
  k_gemm256<u16><<<dim3(16, TOK / 256), 512, 0, stream>>>(kv_n, w_kvb, kvfull, NH * 256, NH * 256, KVL);
  k_rope_pe<<<(TOK * 32) / 256, 256, 0, stream>>>(ac, pos, peR);
  k_pack_v<<<dim3(SS / 64, VD / 64, BB * NH), 256, 0, stream>>>(kvfull, VT);
  // attention: grid (8, B*H), paired q-tiles (x, 15-x)
  k_attn<<<dim3(8, BB * NH), 512, 0, stream>>>(qfull, kvfull, peR, VT, pos, attn_o);
  k_gemm256<float><<<dim3(8, TOK / 256), 512, 0, stream>>>(attn_o, w_o, (float*)d_out, HID, HID, NH * VD);
}

// Round 6
// 350.784 us; speedup vs baseline: 2.5312x; 1.0565x over previous
//
#include <hip/hip_runtime.h>
#include <hip/hip_bf16.h>
#include <stdint.h>
#include <type_traits>

#define DEVINL __device__ __forceinline__

typedef unsigned short u16;
typedef unsigned int   u32;
typedef short bf16x8 __attribute__((ext_vector_type(8)));
typedef float f32x4  __attribute__((ext_vector_type(4)));

// ---- problem constants ----
constexpr int BB   = 2,  SS  = 2048, HID = 2048, NH = 16;
constexpr int NOPE = 128, VD = 128, QHD = 192;
constexpr int QL   = 1536, KVL = 512;
constexpr int TOK  = BB * SS;            // 4096 tokens
constexpr int NCOMB = 2176;              // ac row stride
constexpr int NREAL = 2112;              // real combined output cols (1536+512+64)
constexpr float SCALE2    = 0.10412907368573824f;   // 192^-0.5 * log2(e)
constexpr float LN1E4_32  = 0.28782313662425575f;   // ln(10000)/32

DEVINL float bf2f(u16 u) { union { u32 u; float f; } v; v.u = (u32)u << 16; return v.f; }
DEVINL u16 f2bf(float f) {
  union { float f; u32 u; } v; v.f = f;
  u32 r = v.u + 0x7fffu + ((v.u >> 16) & 1u);
  return (u16)(r >> 16);
}
DEVINL u32 pack2(float a, float b) { return (u32)f2bf(a) | ((u32)f2bf(b) << 16); }

DEVINL float fexp2(float x) {
#if __has_builtin(__builtin_amdgcn_exp2f)
  return __builtin_amdgcn_exp2f(x);
#else
  return __expf(x * 0.6931471805599453f);
#endif
}

DEVINL void gload_lds16(const u16* g, u16* l) {
  __builtin_amdgcn_global_load_lds(
      (const __attribute__((address_space(1))) void*)g,
      (__attribute__((address_space(3))) void*)l, 16, 0, 0);
}

// ---------------- fp32 -> bf16 conversion ----------------
__global__ void k_f2bf(const float* __restrict__ s, u16* __restrict__ d, int n) {
  int i = (blockIdx.x * 256 + threadIdx.x) * 4;
  if (i + 4 <= n) {
    float4 v = *(const float4*)(s + i);
    uint2 o; o.x = pack2(v.x, v.y); o.y = pack2(v.z, v.w);
    *(uint2*)(d + i) = o;
  } else {
    for (; i < n; ++i) d[i] = f2bf(s[i]);
  }
}

// ---------------- 256x256 8-phase NT GEMM body (LDS passed in; callable from grouped kernels) ----------------
template <typename OutT>
DEVINL void gemm256_body(const u16* __restrict__ A, const u16* __restrict__ Bw,
                         OutT* __restrict__ C, int Nld, int Ncap, int K,
                         int m0, int n0, u16* SA, u16* SB) {
  const int t = threadIdx.x;
  const int lane = t & 63, wave = t >> 6;
  const int wr = wave >> 2, wc = wave & 3;
  const int lq = lane & 15, lg = lane >> 4;
  const int NT = K >> 6;

  const int r0 = t >> 3;
  const int cs = ((t & 7) ^ (r0 & 7)) * 8;

  auto stageA = [&](int d, int h, int kt) {
    const u16* g = A + (size_t)(m0 + h * 128) * K + kt * 64;
    u16* l = SA + (d * 2 + h) * 8192;
    gload_lds16(g + (size_t)r0 * K + cs, l + t * 8);
    gload_lds16(g + (size_t)(r0 + 64) * K + cs, l + (t + 512) * 8);
  };
  auto stageB = [&](int d, int h, int kt) {
    const u16* g = Bw + (size_t)(n0 + h * 128) * K + kt * 64;
    u16* l = SB + (d * 2 + h) * 8192;
    gload_lds16(g + (size_t)r0 * K + cs, l + t * 8);
    gload_lds16(g + (size_t)(r0 + 64) * K + cs, l + (t + 512) * 8);
  };
  auto rdA = [&](int d, int m, int k) -> bf16x8 {
    int row = m * 16 + lq;
    return *(const bf16x8*)(SA + (d * 2 + wr) * 8192 + row * 64 + (((k * 4 + lg) ^ (row & 7)) * 8));
  };
  auto rdB = [&](int d, int n, int k) -> bf16x8 {
    int row = (wc & 1) * 64 + n * 16 + lq;
    return *(const bf16x8*)(SB + (d * 2 + (wc >> 1)) * 8192 + row * 64 + (((k * 4 + lg) ^ (row & 7)) * 8));
  };

  f32x4 acc[8][4] = {};
  bf16x8 a[8][2], b[4][2];

  stageA(0, 0, 0); stageA(0, 1, 0); stageB(0, 0, 0); stageB(0, 1, 0);
  if (NT > 1) { stageA(1, 0, 1); stageA(1, 1, 1); stageB(1, 0, 1); }
  asm volatile("s_waitcnt vmcnt(6)" ::: "memory");
  __builtin_amdgcn_s_barrier();

  for (int T = 0; T < NT; ++T) {
    const int d = T & 1;
#pragma unroll
    for (int m = 0; m < 4; ++m) { a[m][0] = rdA(d, m, 0); a[m][1] = rdA(d, m, 1); }
#pragma unroll
    for (int n = 0; n < 2; ++n) { b[n][0] = rdB(d, n, 0); b[n][1] = rdB(d, n, 1); }
    if (T + 1 < NT) stageB(d ^ 1, 1, T + 1);
    asm volatile("s_waitcnt lgkmcnt(8)" ::: "memory");
    __builtin_amdgcn_s_barrier();
    asm volatile("s_waitcnt lgkmcnt(0)" ::: "memory");
    __builtin_amdgcn_s_setprio(1);
#pragma unroll
    for (int m = 0; m < 4; ++m)
#pragma unroll
      for (int n = 0; n < 2; ++n) {
        acc[m][n] = __builtin_amdgcn_mfma_f32_16x16x32_bf16(a[m][0], b[n][0], acc[m][n], 0, 0, 0);
        acc[m][n] = __builtin_amdgcn_mfma_f32_16x16x32_bf16(a[m][1], b[n][1], acc[m][n], 0, 0, 0);
      }
    __builtin_amdgcn_s_setprio(0);
    __builtin_amdgcn_s_barrier();
#pragma unroll
    for (int m = 4; m < 8; ++m) { a[m][0] = rdA(d, m, 0); a[m][1] = rdA(d, m, 1); }
#pragma unroll
    for (int n = 2; n < 4; ++n) { b[n][0] = rdB(d, n, 0); b[n][1] = rdB(d, n, 1); }
    asm volatile("s_waitcnt lgkmcnt(8)" ::: "memory");
    __builtin_amdgcn_s_barrier();
    asm volatile("s_waitcnt lgkmcnt(0)" ::: "memory");
    __builtin_amdgcn_s_setprio(1);
#pragma unroll
    for (int m = 4; m < 8; ++m)
#pragma unroll
      for (int n = 0; n < 2; ++n) {
        acc[m][n] = __builtin_amdgcn_mfma_f32_16x16x32_bf16(a[m][0], b[n][0], acc[m][n], 0, 0, 0);
        acc[m][n] = __builtin_amdgcn_mfma_f32_16x16x32_bf16(a[m][1], b[n][1], acc[m][n], 0, 0, 0);
      }
    __builtin_amdgcn_s_setprio(0);
    __builtin_amdgcn_s_barrier();
    if (T + 2 < NT) { stageA(d, 0, T + 2); stageA(d, 1, T + 2); }
    __builtin_amdgcn_s_barrier();
    __builtin_amdgcn_s_setprio(1);
#pragma unroll
    for (int m = 0; m < 4; ++m)
#pragma unroll
      for (int n = 2; n < 4; ++n) {
        acc[m][n] = __builtin_amdgcn_mfma_f32_16x16x32_bf16(a[m][0], b[n][0], acc[m][n], 0, 0, 0);
        acc[m][n] = __builtin_amdgcn_mfma_f32_16x16x32_bf16(a[m][1], b[n][1], acc[m][n], 0, 0, 0);
      }
    __builtin_amdgcn_s_setprio(0);
    __builtin_amdgcn_s_barrier();
    if (T + 2 < NT) stageB(d, 0, T + 2);
    __builtin_amdgcn_s_barrier();
    __builtin_amdgcn_s_setprio(1);
#pragma unroll
    for (int m = 4; m < 8; ++m)
#pragma unroll
      for (int n = 2; n < 4; ++n) {
        acc[m][n] = __builtin_amdgcn_mfma_f32_16x16x32_bf16(a[m][0], b[n][0], acc[m][n], 0, 0, 0);
        acc[m][n] = __builtin_amdgcn_mfma_f32_16x16x32_bf16(a[m][1], b[n][1], acc[m][n], 0, 0, 0);
      }
    __builtin_amdgcn_s_setprio(0);
    if (T + 2 < NT)      asm volatile("s_waitcnt vmcnt(6)" ::: "memory");
    else if (T + 1 < NT) asm volatile("s_waitcnt vmcnt(0)" ::: "memory");
    __builtin_amdgcn_s_barrier();
  }

#pragma unroll
  for (int m = 0; m < 8; ++m)
#pragma unroll
    for (int n = 0; n < 4; ++n) {
      const int col = n0 + wc * 64 + n * 16 + lq;
      if (col < Ncap) {
        const int row = m0 + wr * 128 + m * 16 + lg * 4;
#pragma unroll
        for (int r = 0; r < 4; ++r) {
          float v = acc[m][n][r];
          if constexpr (std::is_same<OutT, float>::value)
            C[(size_t)(row + r) * Nld + col] = v;
          else
            C[(size_t)(row + r) * Nld + col] = f2bf(v);
        }
      }
    }
}

template <typename OutT>
__global__ __launch_bounds__(512, 2)
void k_gemm256(const u16* __restrict__ A, const u16* __restrict__ Bw,
               OutT* __restrict__ C, int Nld, int Ncap, int K) {
  __shared__ u16 SA[2 * 2 * 8192];
  __shared__ u16 SB[2 * 2 * 8192];
  gemm256_body<OutT>(A, Bw, C, Nld, Ncap, K, blockIdx.y * 256, blockIdx.x * 256, SA, SB);
}

// grouped qb (192 blocks, K=1536, heavy -> first) + kvb (256 blocks, K=512)
__global__ __launch_bounds__(512, 2)
void k_gemm_qbkvb(const u16* __restrict__ qa_n, const u16* __restrict__ w_qb,
                  u16* __restrict__ qfull, const u16* __restrict__ kv_n,
                  const u16* __restrict__ w_kvb, u16* __restrict__ kvfull) {
  __shared__ u16 SA[2 * 2 * 8192];
  __shared__ u16 SB[2 * 2 * 8192];
  const int bx = blockIdx.x;
  if (bx < 192)
    gemm256_body<u16>(qa_n, w_qb, qfull, 3072, 3072, 1536,
                      (bx / 12) * 256, (bx % 12) * 256, SA, SB);
  else {
    const int i = bx - 192;
    gemm256_body<u16>(kv_n, w_kvb, kvfull, 4096, 4096, 512,
                      (i / 16) * 256, (i % 16) * 256, SA, SB);
  }
}

// ---------------- RMSNorm ----------------
__global__ __launch_bounds__(256)
void k_rmsnorm(const u16* __restrict__ x, const float* __restrict__ w,
               u16* __restrict__ y, int D, int xstride) {
  const int row = blockIdx.x;
  const u16* xr = x + (size_t)row * xstride;
  float ss = 0.f;
  for (int i = threadIdx.x; i < D; i += 256) { float v = bf2f(xr[i]); ss += v * v; }
#pragma unroll
  for (int o = 1; o < 64; o <<= 1) ss += __shfl_xor(ss, o);
  __shared__ float red[4];
  if ((threadIdx.x & 63) == 0) red[threadIdx.x >> 6] = ss;
  __syncthreads();
  float rs = rsqrtf((red[0] + red[1] + red[2] + red[3]) / (float)D + 1e-6f);
  u16* yr = y + (size_t)row * D;
  for (int i = threadIdx.x; i < D; i += 256) yr[i] = f2bf(bf2f(xr[i]) * rs * w[i]);
}

// ---------------- rope k_pe: ac[:, 2048:2112] -> peR (B*S, 64) ----------------
__global__ __launch_bounds__(256)
void k_rope_pe(const u16* __restrict__ ac, const int* __restrict__ pos,
               u16* __restrict__ peR) {
  int idx = blockIdx.x * 256 + threadIdx.x;      // TOK*32 pairs
  int token = idx >> 5, j = idx & 31;
  const u16* src = ac + (size_t)token * NCOMB + (QL + KVL) + 2 * j;
  float x0 = bf2f(src[0]), x1 = bf2f(src[1]);
  float ang = (float)pos[token] * __expf(-(float)j * LN1E4_32);
  float sn, cs; sincosf(ang, &sn, &cs);
  *(u32*)(peR + (size_t)token * 64 + 2 * j) = pack2(x0 * cs - x1 * sn, x1 * cs + x0 * sn);
}

// ---------------- pack V^T via LDS-tiled transpose ----------------
__global__ __launch_bounds__(256)
void k_pack_v(const u16* __restrict__ kvf, u16* __restrict__ VT) {
  __shared__ u16 L[64 * 64];
  const int s0 = blockIdx.x * 64, v0 = blockIdx.y * 64;
  const int bh = blockIdx.z, b = bh >> 4, h = bh & 15;
  const int t = threadIdx.x;
  const int sr = t >> 3, vc = (t & 7) * 8;
#pragma unroll
  for (int i = 0; i < 2; ++i) {
    const int r = sr + i * 32;
    const u16* src = kvf + (size_t)(b * SS + s0 + r) * (NH * 256) + h * 256 + NOPE + v0 + vc;
    *(uint4*)(&L[r * 64 + (vc ^ (8 * (r & 7)))]) = *(const uint4*)src;
  }
  __syncthreads();
  const int w = t >> 6, l = t & 63;
  u16 tmp[16];
#pragma unroll
  for (int j = 0; j < 16; ++j) {
    const int r = w * 16 + j;
    tmp[j] = L[r * 64 + (l ^ (8 * (r & 7)))];
  }
  u16* dst = VT + (size_t)(bh * 128 + v0 + l) * SS + s0 + w * 16;
  *(uint4*)dst       = ((uint4*)tmp)[0];
  *(uint4*)(dst + 8) = ((uint4*)tmp)[1];
}

// ---------------- causal flash attention, single-pass blocks for full TLP ----------------
// 1024 blocks x 4 waves (256 thr). Block owns one 64-row q-chunk c, keys [0, 64(c+1)).
// Heavy-first (c = 31 - rank) + bh->XCD grouping: id = {rank[6:0], bh_hi[1:0]... } decoded below;
// id&7 = bh low bits so each XCD streams 4 KV sets. 44KB LDS -> 3 blocks/CU = 3 waves/SIMD.
__global__ __launch_bounds__(256)
void k_attn(const u16* __restrict__ Qf, const u16* __restrict__ kvf,
            const u16* __restrict__ peR, const u16* __restrict__ VT,
            const int* __restrict__ pos, u16* __restrict__ Oa) {
  const int id = blockIdx.x;
  const int xk = id & 7, j = id >> 3;
  const int c = 31 - (j >> 2);
  const int bh = (j & 3) * 8 + xk;
  const int b = bh >> 4, h = bh & 15;
  const int t = threadIdx.x, lane = t & 63, wave = t >> 6;
  const int lq = lane & 15, lg = lane >> 4;
  const int q0 = c * 64 + wave * 16;
  const size_t vb = (size_t)bh * VD * SS;

  __shared__ u16 Ks[2][32 * 192];
  __shared__ u16 Vs[2][128 * 32];
  __shared__ u16 Pl[4][512];
  char* pl = (char*)&Pl[wave][0];
  const int swq = ((lq ^ (lq >> 2)) & 3) << 4;

  auto stage = [&](int buf, int kb) {
#pragma unroll
    for (int i = 0; i < 3; ++i) {      // K: 768 16B chunks
      int cc = t + 256 * i, row = cc / 24, sl = cc % 24;
      int sg = sl ^ (row & 7);
      const u16* src = (sg < 16)
          ? kvf + (size_t)(b * SS + kb + row) * (NH * 256) + h * 256 + sg * 8
          : peR + (size_t)(b * SS + kb + row) * 64 + (sg - 16) * 8;
      gload_lds16(src, &Ks[buf][0] + cc * 8);
    }
#pragma unroll
    for (int i = 0; i < 2; ++i) {      // V: 512 16B chunks
      int cc = t + 256 * i, row = cc >> 2, sl = cc & 3;
      gload_lds16(VT + vb + (size_t)row * SS + kb + (sl ^ ((row >> 1) & 3)) * 8,
                  &Vs[buf][0] + cc * 8);
    }
  };

  const int token = b * SS + q0 + lq;
  bf16x8 qf[6];
#pragma unroll
  for (int ch = 0; ch < 6; ++ch)
    qf[ch] = *(const bf16x8*)(Qf + (size_t)token * (NH * QHD) + h * QHD + ch * 32 + lg * 8);
  // in-reg RoPE on q_pe chunks (4,5)
  const float posv = (float)pos[token];
#pragma unroll
  for (int ch = 4; ch < 6; ++ch)
#pragma unroll
    for (int p = 0; p < 4; ++p) {
      const int jj = (ch - 4) * 16 + lg * 4 + p;
      const float ang = posv * __expf(-(float)jj * LN1E4_32);
      float sn, cs; sincosf(ang, &sn, &cs);
      const float x0 = bf2f((u16)qf[ch][2 * p]), x1 = bf2f((u16)qf[ch][2 * p + 1]);
      qf[ch][2 * p]     = (short)f2bf(x0 * cs - x1 * sn);
      qf[ch][2 * p + 1] = (short)f2bf(x1 * cs + x0 * sn);
    }

  float m = -1e30f, lsum = 0.f;
  f32x4 o[8];
#pragma unroll
  for (int vc = 0; vc < 8; ++vc) o[vc] = (f32x4){0.f, 0.f, 0.f, 0.f};

  const int nt = 2 * (c + 1);

  stage(0, 0);
  asm volatile("s_waitcnt vmcnt(0)" ::: "memory");
  __builtin_amdgcn_s_barrier();

  for (int tt = 0; tt < nt; ++tt) {
    const int cur = tt & 1;
    if (tt + 1 < nt) stage(cur ^ 1, (tt + 1) * 32);
    const int kb = tt * 32;

    if (kb < q0 + 16) {            // wave-uniform skip of fully-masked tiles
      f32x4 slo = (f32x4){0.f, 0.f, 0.f, 0.f};
      f32x4 shi = (f32x4){0.f, 0.f, 0.f, 0.f};
      __builtin_amdgcn_s_setprio(1);
#pragma unroll
      for (int ch = 0; ch < 6; ++ch) {
        const int ps = (ch * 4 + lg) ^ (lq & 7);
        bf16x8 klo = *(const bf16x8*)(&Ks[cur][0] + (lq * 24 + ps) * 8);
        bf16x8 khi = *(const bf16x8*)(&Ks[cur][0] + ((16 + lq) * 24 + ps) * 8);
        slo = __builtin_amdgcn_mfma_f32_16x16x32_bf16(klo, qf[ch], slo, 0, 0, 0);
        shi = __builtin_amdgcn_mfma_f32_16x16x32_bf16(khi, qf[ch], shi, 0, 0, 0);
      }
      __builtin_amdgcn_s_setprio(0);

      const int qrow = q0 + lq;
      float mx = -1e30f;
#pragma unroll
      for (int r = 0; r < 4; ++r) {
        int klo = kb + lg * 4 + r;
        float v0 = (klo <= qrow)        ? slo[r] * SCALE2 : -1e30f;
        float v1 = ((klo + 16) <= qrow) ? shi[r] * SCALE2 : -1e30f;
        slo[r] = v0; shi[r] = v1;
        mx = fmaxf(mx, fmaxf(v0, v1));
      }
      mx = fmaxf(mx, __shfl_xor(mx, 16));
      mx = fmaxf(mx, __shfl_xor(mx, 32));
      if (!__all(mx - m <= 11.0f)) {
        float mnew = fmaxf(m, mx);
        float fac = fexp2(m - mnew);
        lsum *= fac;
#pragma unroll
        for (int vc = 0; vc < 8; ++vc) {
          o[vc][0] *= fac; o[vc][1] *= fac; o[vc][2] *= fac; o[vc][3] *= fac;
        }
        m = mnew;
      }
      float p0 = fexp2(slo[0] - m), p1 = fexp2(slo[1] - m);
      float p2 = fexp2(slo[2] - m), p3 = fexp2(slo[3] - m);
      float p4 = fexp2(shi[0] - m), p5 = fexp2(shi[1] - m);
      float p6 = fexp2(shi[2] - m), p7 = fexp2(shi[3] - m);
      float ps2 = ((p0 + p1) + (p2 + p3)) + ((p4 + p5) + (p6 + p7));
      ps2 += __shfl_xor(ps2, 16);
      ps2 += __shfl_xor(ps2, 32);
      lsum += ps2;

      *(u32*)(pl + lq * 64 + ((8 * lg)          ^ swq)) = pack2(p0, p1);
      *(u32*)(pl + lq * 64 + ((8 * lg + 4)      ^ swq)) = pack2(p2, p3);
      *(u32*)(pl + lq * 64 + ((32 + 8 * lg)     ^ swq)) = pack2(p4, p5);
      *(u32*)(pl + lq * 64 + ((32 + 8 * lg + 4) ^ swq)) = pack2(p6, p7);
      bf16x8 pf = *(const bf16x8*)(pl + lq * 64 + ((16 * lg) ^ swq));
      __builtin_amdgcn_s_setprio(1);
#pragma unroll
      for (int vc = 0; vc < 8; ++vc) {
        const int rv = vc * 16 + lq;
        const int psv = lg ^ ((rv >> 1) & 3);
        bf16x8 vf = *(const bf16x8*)(&Vs[cur][0] + rv * 32 + psv * 8);
        o[vc] = __builtin_amdgcn_mfma_f32_16x16x32_bf16(vf, pf, o[vc], 0, 0, 0);
      }
      __builtin_amdgcn_s_setprio(0);
    }

    asm volatile("s_waitcnt vmcnt(0)" ::: "memory");
    __builtin_amdgcn_s_barrier();
  }

  const float inv = 1.0f / lsum;
  u16* orow = Oa + (size_t)token * (NH * VD) + h * VD;
#pragma unroll
  for (int vc = 0; vc < 8; ++vc) {
    *(u32*)(orow + vc * 16 + lg * 4)     = pack2(o[vc][0] * inv, o[vc][1] * inv);
    *(u32*)(orow + vc * 16 + lg * 4 + 2) = pack2(o[vc][2] * inv, o[vc][3] * inv);
  }
}

// ---------------- host launch ----------------
extern "C" void kernel_launch(void* const* d_in, const int* in_sizes, int n_in,
                              void* d_out, int out_size, void* d_ws, size_t ws_size,
                              hipStream_t stream) {
  (void)in_sizes; (void)n_in; (void)out_size; (void)ws_size;
  const float* hidden  = (const float*)d_in[0];
  const int*   pos     = (const int*)d_in[2];
  const float* q_a_w   = (const float*)d_in[3];
  const float* q_a_ln  = (const float*)d_in[4];
  const float* q_b_w   = (const float*)d_in[5];
  const float* kv_a_w  = (const float*)d_in[6];
  const float* kv_a_ln = (const float*)d_in[7];
  const float* kv_b_w  = (const float*)d_in[8];
  const float* o_w     = (const float*)d_in[9];

  char* ws = (char*)d_ws;
  u16* hid_bf = (u16*)(ws + 0);          // dead after GEMM1; reused as VT
  u16* VT     = (u16*)(ws + 0);
  u16* w_comb = (u16*)(ws + 16777216);
  u16* w_qb   = (u16*)(ws + 25690112);
  u16* w_kvb  = (u16*)(ws + 35127296);
  u16* w_o    = (u16*)(ws + 39321600);
  u16* ac     = (u16*)(ws + 47710208);   // dead after k_rope_pe; reused as attn_o
  u16* attn_o = (u16*)(ws + 47710208);
  u16* qa_n   = (u16*)(ws + 65536000);
  u16* kv_n   = (u16*)(ws + 78118912);
  u16* qfull  = (u16*)(ws + 82313216);
  u16* kvfull = (u16*)(ws + 107479040);
  u16* peR    = (u16*)(ws + 141033472);  // TOK x 64 roped k_pe

  k_f2bf<<<(TOK * HID) / 1024, 256, 0, stream>>>(hidden, hid_bf, TOK * HID);
  k_f2bf<<<(QL * HID) / 1024, 256, 0, stream>>>(q_a_w, w_comb, QL * HID);
  k_f2bf<<<((KVL + 64) * HID) / 1024, 256, 0, stream>>>(kv_a_w, w_comb + QL * HID, (KVL + 64) * HID);
  k_f2bf<<<(NH * QHD * QL) / 1024, 256, 0, stream>>>(q_b_w, w_qb, NH * QHD * QL);
  k_f2bf<<<(NH * 256 * KVL) / 1024, 256, 0, stream>>>(kv_b_w, w_kvb, NH * 256 * KVL);
  k_f2bf<<<(HID * NH * VD) / 1024, 256, 0, stream>>>(o_w, w_o, HID * NH * VD);

  k_gemm256<u16><<<dim3(9, TOK / 256), 512, 0, stream>>>(hid_bf, w_comb, ac, NCOMB, NREAL, HID);
  k_rmsnorm<<<TOK, 256, 0, stream>>>(ac,      q_a_ln,  qa_n, QL,  NCOMB);
  k_rmsnorm<<<TOK, 256, 0, stream>>>(ac + QL, kv_a_ln, kv_n, KVL, NCOMB);
  // grouped q_b + kv_b: 192 + 256 blocks in one launch (qb heavy-first)
  k_gemm_qbkvb<<<448, 512, 0, stream>>>(qa_n, w_qb, qfull, kv_n, w_kvb, kvfull);
  k_rope_pe<<<(TOK * 32) / 256, 256, 0, stream>>>(ac, pos, peR);
  k_pack_v<<<dim3(SS / 64, VD / 64, BB * NH), 256, 0, stream>>>(kvfull, VT);
  // attention: 1024 single-pass blocks, 4 waves each
  k_attn<<<1024, 256, 0, stream>>>(qfull, kvfull, peR, VT, pos, attn_o);
  k_gemm256<float><<<dim3(8, TOK / 256), 512, 0, stream>>>(attn_o, w_o, (float*)d_out, HID, HID, NH * VD);
}

// Round 7
// 316.133 us; speedup vs baseline: 2.8086x; 1.1096x over previous
//
#include <hip/hip_runtime.h>
#include <hip/hip_bf16.h>
#include <stdint.h>
#include <type_traits>

#define DEVINL __device__ __forceinline__

typedef unsigned short u16;
typedef unsigned int   u32;
typedef short bf16x8 __attribute__((ext_vector_type(8)));
typedef float f32x4  __attribute__((ext_vector_type(4)));

// ---- problem constants ----
constexpr int BB   = 2,  SS  = 2048, HID = 2048, NH = 16;
constexpr int NOPE = 128, VD = 128, QHD = 192;
constexpr int QL   = 1536, KVL = 512;
constexpr int TOK  = BB * SS;            // 4096 tokens
constexpr int NCOMB = 2176;              // ac row stride
constexpr int NREAL = 2112;              // real combined output cols (1536+512+64)
constexpr float SCALE2    = 0.10412907368573824f;   // 192^-0.5 * log2(e)
constexpr float THR_RAW   = 105.0f;                 // ~11 / SCALE2 (defer-max, raw units)
constexpr float LN1E4_32  = 0.28782313662425575f;   // ln(10000)/32

DEVINL float bf2f(u16 u) { union { u32 u; float f; } v; v.u = (u32)u << 16; return v.f; }
DEVINL u16 f2bf(float f) {
  union { float f; u32 u; } v; v.f = f;
  u32 r = v.u + 0x7fffu + ((v.u >> 16) & 1u);
  return (u16)(r >> 16);
}
DEVINL u32 pack2(float a, float b) { return (u32)f2bf(a) | ((u32)f2bf(b) << 16); }
DEVINL u32 cvtpk(float lo, float hi) {
  u32 r;
  asm("v_cvt_pk_bf16_f32 %0, %1, %2" : "=v"(r) : "v"(lo), "v"(hi));
  return r;
}

DEVINL float fexp2(float x) {
#if __has_builtin(__builtin_amdgcn_exp2f)
  return __builtin_amdgcn_exp2f(x);
#else
  return __expf(x * 0.6931471805599453f);
#endif
}

DEVINL void gload_lds16(const u16* g, u16* l) {
  __builtin_amdgcn_global_load_lds(
      (const __attribute__((address_space(1))) void*)g,
      (__attribute__((address_space(3))) void*)l, 16, 0, 0);
}

// ---------------- merged fp32 -> bf16 conversion (6 segments, one launch) ----------------
__global__ __launch_bounds__(256)
void k_f2bf_all(const float* __restrict__ s0, const float* __restrict__ s1,
                const float* __restrict__ s2, const float* __restrict__ s3,
                const float* __restrict__ s4, const float* __restrict__ s5,
                u16* __restrict__ d0, u16* __restrict__ d1, u16* __restrict__ d2,
                u16* __restrict__ d3, u16* __restrict__ d4, u16* __restrict__ d5) {
  long g = ((long)blockIdx.x * 256 + threadIdx.x) * 4;
  const float* s; u16* d; long off;
  if (g < 8388608L)       { s = s0; d = d0; off = g; }
  else if (g < 11534336L) { s = s1; d = d1; off = g - 8388608L; }
  else if (g < 12713984L) { s = s2; d = d2; off = g - 11534336L; }
  else if (g < 17432576L) { s = s3; d = d3; off = g - 12713984L; }
  else if (g < 19529728L) { s = s4; d = d4; off = g - 17432576L; }
  else                    { s = s5; d = d5; off = g - 19529728L; }
  float4 v = *(const float4*)(s + off);
  uint2 o; o.x = pack2(v.x, v.y); o.y = pack2(v.z, v.w);
  *(uint2*)(d + off) = o;
}

// ---------------- 256x256 8-phase NT GEMM body with pluggable epilogue ----------------
// epi(row_base, col, f32x4 v): v[r] is C[row_base+r][col].
template <class EPI>
DEVINL void gemm256_body(const u16* __restrict__ A, const u16* __restrict__ Bw,
                         int K, int m0, int n0, u16* SA, u16* SB, EPI epi) {
  const int t = threadIdx.x;
  const int lane = t & 63, wave = t >> 6;
  const int wr = wave >> 2, wc = wave & 3;
  const int lq = lane & 15, lg = lane >> 4;
  const int NT = K >> 6;

  const int r0 = t >> 3;
  const int cs = ((t & 7) ^ (r0 & 7)) * 8;

  auto stageA = [&](int d, int h, int kt) {
    const u16* g = A + (size_t)(m0 + h * 128) * K + kt * 64;
    u16* l = SA + (d * 2 + h) * 8192;
    gload_lds16(g + (size_t)r0 * K + cs, l + t * 8);
    gload_lds16(g + (size_t)(r0 + 64) * K + cs, l + (t + 512) * 8);
  };
  auto stageB = [&](int d, int h, int kt) {
    const u16* g = Bw + (size_t)(n0 + h * 128) * K + kt * 64;
    u16* l = SB + (d * 2 + h) * 8192;
    gload_lds16(g + (size_t)r0 * K + cs, l + t * 8);
    gload_lds16(g + (size_t)(r0 + 64) * K + cs, l + (t + 512) * 8);
  };
  auto rdA = [&](int d, int m, int k) -> bf16x8 {
    int row = m * 16 + lq;
    return *(const bf16x8*)(SA + (d * 2 + wr) * 8192 + row * 64 + (((k * 4 + lg) ^ (row & 7)) * 8));
  };
  auto rdB = [&](int d, int n, int k) -> bf16x8 {
    int row = (wc & 1) * 64 + n * 16 + lq;
    return *(const bf16x8*)(SB + (d * 2 + (wc >> 1)) * 8192 + row * 64 + (((k * 4 + lg) ^ (row & 7)) * 8));
  };

  f32x4 acc[8][4] = {};
  bf16x8 a[8][2], b[4][2];

  stageA(0, 0, 0); stageA(0, 1, 0); stageB(0, 0, 0); stageB(0, 1, 0);
  if (NT > 1) { stageA(1, 0, 1); stageA(1, 1, 1); stageB(1, 0, 1); }
  asm volatile("s_waitcnt vmcnt(6)" ::: "memory");
  __builtin_amdgcn_s_barrier();

  for (int T = 0; T < NT; ++T) {
    const int d = T & 1;
#pragma unroll
    for (int m = 0; m < 4; ++m) { a[m][0] = rdA(d, m, 0); a[m][1] = rdA(d, m, 1); }
#pragma unroll
    for (int n = 0; n < 2; ++n) { b[n][0] = rdB(d, n, 0); b[n][1] = rdB(d, n, 1); }
    if (T + 1 < NT) stageB(d ^ 1, 1, T + 1);
    asm volatile("s_waitcnt lgkmcnt(8)" ::: "memory");
    __builtin_amdgcn_s_barrier();
    asm volatile("s_waitcnt lgkmcnt(0)" ::: "memory");
    __builtin_amdgcn_s_setprio(1);
#pragma unroll
    for (int m = 0; m < 4; ++m)
#pragma unroll
      for (int n = 0; n < 2; ++n) {
        acc[m][n] = __builtin_amdgcn_mfma_f32_16x16x32_bf16(a[m][0], b[n][0], acc[m][n], 0, 0, 0);
        acc[m][n] = __builtin_amdgcn_mfma_f32_16x16x32_bf16(a[m][1], b[n][1], acc[m][n], 0, 0, 0);
      }
    __builtin_amdgcn_s_setprio(0);
    __builtin_amdgcn_s_barrier();
#pragma unroll
    for (int m = 4; m < 8; ++m) { a[m][0] = rdA(d, m, 0); a[m][1] = rdA(d, m, 1); }
#pragma unroll
    for (int n = 2; n < 4; ++n) { b[n][0] = rdB(d, n, 0); b[n][1] = rdB(d, n, 1); }
    asm volatile("s_waitcnt lgkmcnt(8)" ::: "memory");
    __builtin_amdgcn_s_barrier();
    asm volatile("s_waitcnt lgkmcnt(0)" ::: "memory");
    __builtin_amdgcn_s_setprio(1);
#pragma unroll
    for (int m = 4; m < 8; ++m)
#pragma unroll
      for (int n = 0; n < 2; ++n) {
        acc[m][n] = __builtin_amdgcn_mfma_f32_16x16x32_bf16(a[m][0], b[n][0], acc[m][n], 0, 0, 0);
        acc[m][n] = __builtin_amdgcn_mfma_f32_16x16x32_bf16(a[m][1], b[n][1], acc[m][n], 0, 0, 0);
      }
    __builtin_amdgcn_s_setprio(0);
    __builtin_amdgcn_s_barrier();
    if (T + 2 < NT) { stageA(d, 0, T + 2); stageA(d, 1, T + 2); }
    __builtin_amdgcn_s_barrier();
    __builtin_amdgcn_s_setprio(1);
#pragma unroll
    for (int m = 0; m < 4; ++m)
#pragma unroll
      for (int n = 2; n < 4; ++n) {
        acc[m][n] = __builtin_amdgcn_mfma_f32_16x16x32_bf16(a[m][0], b[n][0], acc[m][n], 0, 0, 0);
        acc[m][n] = __builtin_amdgcn_mfma_f32_16x16x32_bf16(a[m][1], b[n][1], acc[m][n], 0, 0, 0);
      }
    __builtin_amdgcn_s_setprio(0);
    __builtin_amdgcn_s_barrier();
    if (T + 2 < NT) stageB(d, 0, T + 2);
    __builtin_amdgcn_s_barrier();
    __builtin_amdgcn_s_setprio(1);
#pragma unroll
    for (int m = 4; m < 8; ++m)
#pragma unroll
      for (int n = 2; n < 4; ++n) {
        acc[m][n] = __builtin_amdgcn_mfma_f32_16x16x32_bf16(a[m][0], b[n][0], acc[m][n], 0, 0, 0);
        acc[m][n] = __builtin_amdgcn_mfma_f32_16x16x32_bf16(a[m][1], b[n][1], acc[m][n], 0, 0, 0);
      }
    __builtin_amdgcn_s_setprio(0);
    if (T + 2 < NT)      asm volatile("s_waitcnt vmcnt(6)" ::: "memory");
    else if (T + 1 < NT) asm volatile("s_waitcnt vmcnt(0)" ::: "memory");
    __builtin_amdgcn_s_barrier();
  }

#pragma unroll
  for (int m = 0; m < 8; ++m)
#pragma unroll
    for (int n = 0; n < 4; ++n)
      epi(m0 + wr * 128 + m * 16 + lg * 4, n0 + wc * 64 + n * 16 + lq, acc[m][n]);
}

// GEMM1: hidden @ w_comb^T -> ac (guarded cols)
__global__ __launch_bounds__(512, 2)
void k_gemm1(const u16* __restrict__ A, const u16* __restrict__ Bw, u16* __restrict__ C) {
  __shared__ u16 SA[2 * 2 * 8192];
  __shared__ u16 SB[2 * 2 * 8192];
  auto epi = [&](int row, int col, const f32x4& v) {
    if (col < NREAL) {
#pragma unroll
      for (int r = 0; r < 4; ++r) C[(size_t)(row + r) * NCOMB + col] = f2bf(v[r]);
    }
  };
  gemm256_body(A, Bw, HID, blockIdx.y * 256, blockIdx.x * 256, SA, SB, epi);
}

// grouped qb (192 blocks) + kvb (256 blocks, epilogue splits KN / VT-transposed)
__global__ __launch_bounds__(512, 2)
void k_gemm_qbkvb(const u16* __restrict__ qa_n, const u16* __restrict__ w_qb,
                  u16* __restrict__ qfull, const u16* __restrict__ kv_n,
                  const u16* __restrict__ w_kvb, u16* __restrict__ KN,
                  u16* __restrict__ VT) {
  __shared__ u16 SA[2 * 2 * 8192];
  __shared__ u16 SB[2 * 2 * 8192];
  const int bx = blockIdx.x;
  if (bx < 192) {
    auto epi = [&](int row, int col, const f32x4& v) {
#pragma unroll
      for (int r = 0; r < 4; ++r) qfull[(size_t)(row + r) * 3072 + col] = f2bf(v[r]);
    };
    gemm256_body(qa_n, w_qb, QL, (bx / 12) * 256, (bx % 12) * 256, SA, SB, epi);
  } else {
    const int i = bx - 192;
    auto epi = [&](int row, int col, const f32x4& v) {
      const int h = col >> 8, d = col & 255;
      if (d < 128) {
#pragma unroll
        for (int r = 0; r < 4; ++r) KN[(size_t)(row + r) * 2048 + h * 128 + d] = f2bf(v[r]);
      } else {
        uint2 o; o.x = pack2(v[0], v[1]); o.y = pack2(v[2], v[3]);
        *(uint2*)(VT + ((size_t)((row >> 11) * 16 + h) * 128 + (d - 128)) * SS + (row & (SS - 1))) = o;
      }
    };
    gemm256_body(kv_n, w_kvb, KVL, (i / 16) * 256, (i % 16) * 256, SA, SB, epi);
  }
}

// o_proj -> fp32 d_out
__global__ __launch_bounds__(512, 2)
void k_oproj(const u16* __restrict__ A, const u16* __restrict__ Bw, float* __restrict__ C) {
  __shared__ u16 SA[2 * 2 * 8192];
  __shared__ u16 SB[2 * 2 * 8192];
  auto epi = [&](int row, int col, const f32x4& v) {
#pragma unroll
    for (int r = 0; r < 4; ++r) C[(size_t)(row + r) * HID + col] = v[r];
  };
  gemm256_body(A, Bw, NH * VD, blockIdx.y * 256, blockIdx.x * 256, SA, SB, epi);
}

// ---------------- fused per-token: RMSNorm(q), RMSNorm(kv), rope(k_pe) ----------------
__global__ __launch_bounds__(256)
void k_token(const u16* __restrict__ ac, const float* __restrict__ qw,
             const float* __restrict__ kvw, const int* __restrict__ pos,
             u16* __restrict__ qa_n, u16* __restrict__ kv_n, u16* __restrict__ peR) {
  const int row = blockIdx.x, t = threadIdx.x;
  const u16* xr = ac + (size_t)row * NCOMB;
  float sq = 0.f, skv = 0.f;
  if (t < 192) {
    bf16x8 v = *(const bf16x8*)(xr + t * 8);
#pragma unroll
    for (int j = 0; j < 8; ++j) { float f = bf2f((u16)v[j]); sq += f * f; }
  }
  if (t < 64) {
    bf16x8 v = *(const bf16x8*)(xr + QL + t * 8);
#pragma unroll
    for (int j = 0; j < 8; ++j) { float f = bf2f((u16)v[j]); skv += f * f; }
  }
#pragma unroll
  for (int o = 1; o < 64; o <<= 1) { sq += __shfl_xor(sq, o); skv += __shfl_xor(skv, o); }
  __shared__ float red[4][2];
  if ((t & 63) == 0) { red[t >> 6][0] = sq; red[t >> 6][1] = skv; }
  __syncthreads();
  const float rsq  = rsqrtf((red[0][0] + red[1][0] + red[2][0] + red[3][0]) / (float)QL  + 1e-6f);
  const float rskv = rsqrtf((red[0][1] + red[1][1] + red[2][1] + red[3][1]) / (float)KVL + 1e-6f);
  if (t < 192) {
    bf16x8 v = *(const bf16x8*)(xr + t * 8);
    u32 o4[4];
#pragma unroll
    for (int j = 0; j < 4; ++j)
      o4[j] = pack2(bf2f((u16)v[2 * j]) * rsq * qw[t * 8 + 2 * j],
                    bf2f((u16)v[2 * j + 1]) * rsq * qw[t * 8 + 2 * j + 1]);
    *(uint4*)(qa_n + (size_t)row * QL + t * 8) = *(uint4*)o4;
  }
  if (t < 64) {
    bf16x8 v = *(const bf16x8*)(xr + QL + t * 8);
    u32 o4[4];
#pragma unroll
    for (int j = 0; j < 4; ++j)
      o4[j] = pack2(bf2f((u16)v[2 * j]) * rskv * kvw[t * 8 + 2 * j],
                    bf2f((u16)v[2 * j + 1]) * rskv * kvw[t * 8 + 2 * j + 1]);
    *(uint4*)(kv_n + (size_t)row * KVL + t * 8) = *(uint4*)o4;
  }
  if (t < 32) {
    const u16* src = xr + (QL + KVL) + 2 * t;
    float x0 = bf2f(src[0]), x1 = bf2f(src[1]);
    float ang = (float)pos[row] * __expf(-(float)t * LN1E4_32);
    float sn, cs; sincosf(ang, &sn, &cs);
    *(u32*)(peR + (size_t)row * 64 + 2 * t) = pack2(x0 * cs - x1 * sn, x1 * cs + x0 * sn);
  }
}

// ---------------- causal flash attention (VALU-dieted softmax) ----------------
// 1024 blocks x 4 waves. Interior tiles (kb+32 <= q0) skip masking entirely;
// raw-domain max + fma-folded scale into exp2; cvt_pk P-pack.
__global__ __launch_bounds__(256)
void k_attn(const u16* __restrict__ Qf, const u16* __restrict__ KN,
            const u16* __restrict__ peR, const u16* __restrict__ VT,
            const int* __restrict__ pos, u16* __restrict__ Oa) {
  const int id = blockIdx.x;
  const int xk = id & 7, j = id >> 3;
  const int c = 31 - (j >> 2);
  const int bh = (j & 3) * 8 + xk;
  const int b = bh >> 4, h = bh & 15;
  const int t = threadIdx.x, lane = t & 63, wave = t >> 6;
  const int lq = lane & 15, lg = lane >> 4;
  const int q0 = c * 64 + wave * 16;
  const size_t vb = (size_t)bh * VD * SS;

  __shared__ u16 Ks[2][32 * 192];
  __shared__ u16 Vs[2][128 * 32];
  __shared__ u16 Pl[4][512];
  char* pl = (char*)&Pl[wave][0];
  const int swq = ((lq ^ (lq >> 2)) & 3) << 4;

  auto stage = [&](int buf, int kb) {
#pragma unroll
    for (int i = 0; i < 3; ++i) {      // K: 768 16B chunks (nope from KN, pe from peR)
      int cc = t + 256 * i, row = cc / 24, sl = cc % 24;
      int sg = sl ^ (row & 7);
      const u16* src = (sg < 16)
          ? KN + (size_t)(b * SS + kb + row) * 2048 + h * 128 + sg * 8
          : peR + (size_t)(b * SS + kb + row) * 64 + (sg - 16) * 8;
      gload_lds16(src, &Ks[buf][0] + cc * 8);
    }
#pragma unroll
    for (int i = 0; i < 2; ++i) {      // V: 512 16B chunks
      int cc = t + 256 * i, row = cc >> 2, sl = cc & 3;
      gload_lds16(VT + vb + (size_t)row * SS + kb + (sl ^ ((row >> 1) & 3)) * 8,
                  &Vs[buf][0] + cc * 8);
    }
  };

  const int token = b * SS + q0 + lq;
  bf16x8 qf[6];
#pragma unroll
  for (int ch = 0; ch < 6; ++ch)
    qf[ch] = *(const bf16x8*)(Qf + (size_t)token * (NH * QHD) + h * QHD + ch * 32 + lg * 8);
  // in-reg RoPE on q_pe chunks (4,5)
  const float posv = (float)pos[token];
#pragma unroll
  for (int ch = 4; ch < 6; ++ch)
#pragma unroll
    for (int p = 0; p < 4; ++p) {
      const int jj = (ch - 4) * 16 + lg * 4 + p;
      const float ang = posv * __expf(-(float)jj * LN1E4_32);
      float sn, cs; sincosf(ang, &sn, &cs);
      const float x0 = bf2f((u16)qf[ch][2 * p]), x1 = bf2f((u16)qf[ch][2 * p + 1]);
      qf[ch][2 * p]     = (short)f2bf(x0 * cs - x1 * sn);
      qf[ch][2 * p + 1] = (short)f2bf(x1 * cs + x0 * sn);
    }

  float m = -1e30f, lsum = 0.f;     // m in RAW score units
  f32x4 o[8];
#pragma unroll
  for (int vc = 0; vc < 8; ++vc) o[vc] = (f32x4){0.f, 0.f, 0.f, 0.f};

  const int nt = 2 * (c + 1);

  stage(0, 0);
  asm volatile("s_waitcnt vmcnt(0)" ::: "memory");
  __builtin_amdgcn_s_barrier();

  for (int tt = 0; tt < nt; ++tt) {
    const int cur = tt & 1;
    if (tt + 1 < nt) stage(cur ^ 1, (tt + 1) * 32);
    const int kb = tt * 32;

    if (kb < q0 + 16) {            // wave-uniform skip of fully-masked tiles
      f32x4 slo = (f32x4){0.f, 0.f, 0.f, 0.f};
      f32x4 shi = (f32x4){0.f, 0.f, 0.f, 0.f};
      __builtin_amdgcn_s_setprio(1);
#pragma unroll
      for (int ch = 0; ch < 6; ++ch) {
        const int ps = (ch * 4 + lg) ^ (lq & 7);
        bf16x8 klo = *(const bf16x8*)(&Ks[cur][0] + (lq * 24 + ps) * 8);
        bf16x8 khi = *(const bf16x8*)(&Ks[cur][0] + ((16 + lq) * 24 + ps) * 8);
        slo = __builtin_amdgcn_mfma_f32_16x16x32_bf16(klo, qf[ch], slo, 0, 0, 0);
        shi = __builtin_amdgcn_mfma_f32_16x16x32_bf16(khi, qf[ch], shi, 0, 0, 0);
      }
      __builtin_amdgcn_s_setprio(0);

      float mx;
      if (kb + 32 <= q0) {         // interior tile: no lane masked
        mx = fmaxf(fmaxf(fmaxf(slo[0], slo[1]), fmaxf(slo[2], slo[3])),
                   fmaxf(fmaxf(shi[0], shi[1]), fmaxf(shi[2], shi[3])));
      } else {                     // diagonal tile: mask in raw domain
        const int qrow = q0 + lq;
#pragma unroll
        for (int r = 0; r < 4; ++r) {
          int klo = kb + lg * 4 + r;
          slo[r] = (klo <= qrow)        ? slo[r] : -3e38f;
          shi[r] = ((klo + 16) <= qrow) ? shi[r] : -3e38f;
        }
        mx = fmaxf(fmaxf(fmaxf(slo[0], slo[1]), fmaxf(slo[2], slo[3])),
                   fmaxf(fmaxf(shi[0], shi[1]), fmaxf(shi[2], shi[3])));
      }
      mx = fmaxf(mx, __shfl_xor(mx, 16));
      mx = fmaxf(mx, __shfl_xor(mx, 32));
      if (!__all(mx - m <= THR_RAW)) {
        float mnew = fmaxf(m, mx);
        float fac = fexp2((m - mnew) * SCALE2);
        lsum *= fac;
#pragma unroll
        for (int vc = 0; vc < 8; ++vc) {
          o[vc][0] *= fac; o[vc][1] *= fac; o[vc][2] *= fac; o[vc][3] *= fac;
        }
        m = mnew;
      }
      const float ms = m * SCALE2;
      float p0 = fexp2(fmaf(slo[0], SCALE2, -ms)), p1 = fexp2(fmaf(slo[1], SCALE2, -ms));
      float p2 = fexp2(fmaf(slo[2], SCALE2, -ms)), p3 = fexp2(fmaf(slo[3], SCALE2, -ms));
      float p4 = fexp2(fmaf(shi[0], SCALE2, -ms)), p5 = fexp2(fmaf(shi[1], SCALE2, -ms));
      float p6 = fexp2(fmaf(shi[2], SCALE2, -ms)), p7 = fexp2(fmaf(shi[3], SCALE2, -ms));
      float ps2 = ((p0 + p1) + (p2 + p3)) + ((p4 + p5) + (p6 + p7));
      ps2 += __shfl_xor(ps2, 16);
      ps2 += __shfl_xor(ps2, 32);
      lsum += ps2;

      *(u32*)(pl + lq * 64 + ((8 * lg)          ^ swq)) = cvtpk(p0, p1);
      *(u32*)(pl + lq * 64 + ((8 * lg + 4)      ^ swq)) = cvtpk(p2, p3);
      *(u32*)(pl + lq * 64 + ((32 + 8 * lg)     ^ swq)) = cvtpk(p4, p5);
      *(u32*)(pl + lq * 64 + ((32 + 8 * lg + 4) ^ swq)) = cvtpk(p6, p7);
      bf16x8 pf = *(const bf16x8*)(pl + lq * 64 + ((16 * lg) ^ swq));
      __builtin_amdgcn_s_setprio(1);
#pragma unroll
      for (int vc = 0; vc < 8; ++vc) {
        const int rv = vc * 16 + lq;
        const int psv = lg ^ ((rv >> 1) & 3);
        bf16x8 vf = *(const bf16x8*)(&Vs[cur][0] + rv * 32 + psv * 8);
        o[vc] = __builtin_amdgcn_mfma_f32_16x16x32_bf16(vf, pf, o[vc], 0, 0, 0);
      }
      __builtin_amdgcn_s_setprio(0);
    }

    asm volatile("s_waitcnt vmcnt(0)" ::: "memory");
    __builtin_amdgcn_s_barrier();
  }

  const float inv = 1.0f / lsum;
  u16* orow = Oa + (size_t)token * (NH * VD) + h * VD;
#pragma unroll
  for (int vc = 0; vc < 8; ++vc) {
    *(u32*)(orow + vc * 16 + lg * 4)     = cvtpk(o[vc][0] * inv, o[vc][1] * inv);
    *(u32*)(orow + vc * 16 + lg * 4 + 2) = cvtpk(o[vc][2] * inv, o[vc][3] * inv);
  }
}

// ---------------- host launch ----------------
extern "C" void kernel_launch(void* const* d_in, const int* in_sizes, int n_in,
                              void* d_out, int out_size, void* d_ws, size_t ws_size,
                              hipStream_t stream) {
  (void)in_sizes; (void)n_in; (void)out_size; (void)ws_size;
  const float* hidden  = (const float*)d_in[0];
  const int*   pos     = (const int*)d_in[2];
  const float* q_a_w   = (const float*)d_in[3];
  const float* q_a_ln  = (const float*)d_in[4];
  const float* q_b_w   = (const float*)d_in[5];
  const float* kv_a_w  = (const float*)d_in[6];
  const float* kv_a_ln = (const float*)d_in[7];
  const float* kv_b_w  = (const float*)d_in[8];
  const float* o_w     = (const float*)d_in[9];

  char* ws = (char*)d_ws;
  u16* hid_bf = (u16*)(ws + 0);          // dead after GEMM1; region reused as VT
  u16* VT     = (u16*)(ws + 0);
  u16* w_comb = (u16*)(ws + 16777216);
  u16* w_qb   = (u16*)(ws + 25690112);
  u16* w_kvb  = (u16*)(ws + 35127296);
  u16* w_o    = (u16*)(ws + 39321600);
  u16* ac     = (u16*)(ws + 47710208);   // dead after k_token; reused as attn_o
  u16* attn_o = (u16*)(ws + 47710208);
  u16* qa_n   = (u16*)(ws + 65536000);
  u16* kv_n   = (u16*)(ws + 78118912);
  u16* qfull  = (u16*)(ws + 82313216);
  u16* KN     = (u16*)(ws + 107479040);  // TOK x 2048 compact k_nope
  u16* peR    = (u16*)(ws + 141033472);  // TOK x 64 roped k_pe

  // all fp32->bf16 conversions in one launch (23,724,032 elems / 1024 per block)
  k_f2bf_all<<<23168, 256, 0, stream>>>(hidden, q_a_w, kv_a_w, q_b_w, kv_b_w, o_w,
                                        hid_bf, w_comb, w_comb + QL * HID, w_qb, w_kvb, w_o);
  k_gemm1<<<dim3(9, TOK / 256), 512, 0, stream>>>(hid_bf, w_comb, ac);
  k_token<<<TOK, 256, 0, stream>>>(ac, q_a_ln, kv_a_ln, pos, qa_n, kv_n, peR);
  k_gemm_qbkvb<<<448, 512, 0, stream>>>(qa_n, w_qb, qfull, kv_n, w_kvb, KN, VT);
  k_attn<<<1024, 256, 0, stream>>>(qfull, KN, peR, VT, pos, attn_o);
  k_oproj<<<dim3(8, TOK / 256), 512, 0, stream>>>(attn_o, w_o, (float*)d_out);
}